// Round 19
// baseline (312.315 us; speedup 1.0000x reference)
//
#include <hip/hip_runtime.h>
#include <hip/hip_fp16.h>
#include <float.h>

// ---- fixed problem shape ----
constexpr int NB  = 16;     // batch (clouds)
constexpr int NPT = 2048;   // points per cloud
constexpr int KK  = 20;     // kNN
constexpr int NEDGE = NB * NPT * KK;       // 655360
constexpr int C1 = 64, C2 = 128, EMB = 1024, OUT = 7;
constexpr int NNODE = NB * NPT;            // 32768
constexpr int E2_BLOCKS = 1024;            // edge2 grid (4 tiles each)
constexpr int N_E2_PART = 1024;            // edge2 stat partials (1 per block)
constexpr int GRAM_GRID = 256;             // one block per CU, 2 tiles each
constexpr int GRAM_ELEMS = C2 * C2 + C2;   // 16512 (Gram + colsum)
__device__ constexpr double R1d = (double)NEDGE;       // BN1/BN2 row count
__device__ constexpr double R3d = (double)(NB * NPT);  // BN3 row count

using half2_t = _Float16 __attribute__((ext_vector_type(2)));
using half4_t = _Float16 __attribute__((ext_vector_type(4)));
using float4_t = float __attribute__((ext_vector_type(4)));

static __device__ __forceinline__ unsigned long long ullmin2(unsigned long long a, unsigned long long b) {
  return a < b ? a : b;
}

// ---------------- pos pack: (x,y,z,|p|^2) per point ----------------
__global__ __launch_bounds__(256) void packpos_kernel(const float* __restrict__ pos, float4* __restrict__ pos4) {
  int i = blockIdx.x * 256 + threadIdx.x;   // 32768
  float x = pos[i * 3], y = pos[i * 3 + 1], z = pos[i * 3 + 2];
  pos4[i] = make_float4(x, y, z, x * x + y * y + z * z);
}

// ---------------- kNN v9: pos4 loads + u32 first-stage selection ----------------
// Bound stage needs only dist-bits: running umin32 during key build (replaces the
// u64 lane-min tree) + u32 bitonic of the 64 lane-mins. d20 = 20th smallest
// lane-min dist-bits; survivors = keys with distbits <= d20 (superset of top-20:
// the 20 smallest lane-mins are distinct keys with distbits <= d20). Survivor
// sort stays exact u64 (full (dist,idx) order = jax.lax.top_k ties).
__global__ __launch_bounds__(256) void knn_kernel(const float4* __restrict__ pos4, unsigned short* __restrict__ idxo) {
  __shared__ unsigned long long surv[4][128];   // 4 KiB
  int t = threadIdx.x;
  int lane = t & 63, w = t >> 6;
  int bn = blockIdx.x * 4 + w;            // 8192 blocks x 4 waves = 32768 queries
  int b = bn >> 11, n = bn & (NPT - 1);
  const float4* pb = pos4 + (size_t)b * NPT;
  float4 pq = pb[n];
  float xn = pq.x, yn = pq.y, zn = pq.z, sqn = pq.w;

  unsigned long long key[32];
  unsigned dmin = 0xffffffffu;
  #pragma unroll
  for (int i = 0; i < 32; ++i) {
    int m = i * 64 + lane;
    float4 pm = pb[m];
    float dt = xn * pm.x + yn * pm.y + zn * pm.z;
    float d = sqn + pm.w - 2.0f * dt;
    unsigned ub = __float_as_uint(d);
    ub = (ub & 0x80000000u) ? ~ub : (ub | 0x80000000u);  // order-preserving map
    key[i] = ((unsigned long long)ub << 32) | (unsigned long long)(unsigned)m;
    dmin = dmin < ub ? dmin : ub;
  }

  // bitonic sort of the 64 lane-min dist-bits (u32, ascending by lane)
  unsigned v = dmin;
  #pragma unroll
  for (int k = 2; k <= 64; k <<= 1) {
    #pragma unroll
    for (int j = k >> 1; j > 0; j >>= 1) {
      unsigned o = (unsigned)__shfl_xor((int)v, j, 64);
      bool up = ((lane & k) == 0);
      bool lower = ((lane & j) == 0);
      unsigned mn = v < o ? v : o;
      unsigned mx = v < o ? o : v;
      v = (lower == up) ? mn : mx;
    }
  }
  unsigned d20 = (unsigned)__shfl((int)v, 19, 64);  // 20th smallest lane-min dist-bits

  // compact survivors (distbits <= d20) into LDS
  unsigned long long* sv = surv[w];
  unsigned total = 0;
  #pragma unroll
  for (int i = 0; i < 32; ++i) {
    bool p = (unsigned)(key[i] >> 32) <= d20;
    unsigned long long mask = __ballot(p);
    unsigned pre = __builtin_amdgcn_mbcnt_hi((unsigned)(mask >> 32),
                   __builtin_amdgcn_mbcnt_lo((unsigned)mask, 0));
    unsigned posi = total + pre;
    if (p && posi < 128u) sv[posi] = key[i];
    total += (unsigned)__popcll(mask);
  }

  if (total <= 64u) {
    // fast path: one u64 bitonic sort of <=64 survivors (INF-padded)
    unsigned long long s = (lane < (int)total) ? sv[lane] : ~0ull;
    #pragma unroll
    for (int k = 2; k <= 64; k <<= 1) {
      #pragma unroll
      for (int j = k >> 1; j > 0; j >>= 1) {
        unsigned long long o = (unsigned long long)__shfl_xor((long long)s, j, 64);
        bool up = ((lane & k) == 0);
        bool lower = ((lane & j) == 0);
        unsigned long long mn = s < o ? s : o;
        unsigned long long mx = s < o ? o : s;
        s = (lower == up) ? mn : mx;
      }
    }
    if (lane < KK) idxo[(size_t)bn * KK + lane] = (unsigned short)(unsigned)(s & 0xffffffffull);
    return;
  }

  unsigned long long T = 0;
  int myidx = 0;
  if (total <= 128u) {
    unsigned long long s0 = (lane < (int)total) ? sv[lane] : ~0ull;
    unsigned long long s1 = (lane + 64 < (int)total) ? sv[lane + 64] : ~0ull;
    for (int r = 0; r < KK; ++r) {
      unsigned long long best = ullmin2(s0 - T, s1 - T);  // consumed (<T) wrap high
      #pragma unroll
      for (int off = 32; off > 0; off >>= 1) {
        unsigned long long o = (unsigned long long)__shfl_xor((long long)best, off, 64);
        best = ullmin2(best, o);
      }
      unsigned long long winner = best + T;
      if (lane == r) myidx = (int)(unsigned)(winner & 0xffffffffull);
      T = winner + 1;
    }
  } else {
    for (int r = 0; r < KK; ++r) {
      unsigned long long u0[16];
      #pragma unroll
      for (int i = 0; i < 16; ++i)
        u0[i] = ullmin2(key[2 * i] - T, key[2 * i + 1] - T);
      #pragma unroll
      for (int s = 8; s > 0; s >>= 1)
        #pragma unroll
        for (int i = 0; i < 8; ++i)
          if (i < s) u0[i] = ullmin2(u0[i], u0[i + s]);
      unsigned long long best = u0[0];
      #pragma unroll
      for (int off = 32; off > 0; off >>= 1) {
        unsigned long long o = (unsigned long long)__shfl_xor((long long)best, off, 64);
        best = ullmin2(best, o);
      }
      unsigned long long winner = best + T;
      if (lane == r) myidx = (int)(unsigned)(winner & 0xffffffffull);
      T = winner + 1;
    }
  }
  if (lane < KK) idxo[(size_t)bn * KK + lane] = (unsigned short)(unsigned)myidx;
}

// ---------------- edge-feature first/second moments (6 + 21 doubles) ----------------
__global__ __launch_bounds__(256) void statse_kernel(const float4* __restrict__ pos4, const unsigned short* __restrict__ idx,
                                                     double* __restrict__ dstats) {
  float acc[27];
  #pragma unroll
  for (int i = 0; i < 27; ++i) acc[i] = 0.f;
  int t = threadIdx.x;
  for (int e = blockIdx.x * 256 + t; e < NEDGE; e += gridDim.x * 256) {
    int bn = e / KK;
    int b = bn >> 11, n = bn & (NPT - 1);
    int j = idx[e];
    const float4* pb = pos4 + (size_t)b * NPT;
    float4 pn = pb[n];
    float4 pj = pb[j];
    float f[6];
    f[0] = pn.x; f[1] = pn.y; f[2] = pn.z;
    f[3] = pj.x - pn.x; f[4] = pj.y - pn.y; f[5] = pj.z - pn.z;
    int p = 6;
    #pragma unroll
    for (int d = 0; d < 6; ++d) acc[d] += f[d];
    #pragma unroll
    for (int d = 0; d < 6; ++d)
      #pragma unroll
      for (int q = d; q < 6; ++q) { acc[p] += f[d] * f[q]; ++p; }
  }
  __shared__ float sred[4][27];
  int lane = t & 63, w = t >> 6;
  #pragma unroll
  for (int c = 0; c < 27; ++c) {
    float v = acc[c];
    #pragma unroll
    for (int off = 32; off > 0; off >>= 1) v += __shfl_down(v, off);
    if (lane == 0) sred[w][c] = v;
  }
  __syncthreads();
  if (t < 27) {
    double s = (double)sred[0][t] + (double)sred[1][t] + (double)sred[2][t] + (double)sred[3][t];
    atomicAdd(&dstats[t], s);
  }
}

// ---------------- BN1 coeffs from moments ----------------
__global__ void finalize1_kernel(const double* __restrict__ dstats, const float* __restrict__ W1,
                                 const float* __restrict__ b1, const float* __restrict__ g1,
                                 const float* __restrict__ be1, float* __restrict__ scale1,
                                 float* __restrict__ shift1) {
  int c = threadIdx.x;  // 64
  double m1[6], M2[6][6];
  for (int d = 0; d < 6; ++d) m1[d] = dstats[d];
  int p = 6;
  for (int d = 0; d < 6; ++d)
    for (int q = d; q < 6; ++q) { M2[d][q] = dstats[p]; M2[q][d] = dstats[p]; ++p; }
  double w[6];
  for (int d = 0; d < 6; ++d) w[d] = W1[d * C1 + c];
  double wm = 0, quad = 0;
  for (int d = 0; d < 6; ++d) wm += w[d] * m1[d];
  for (int d = 0; d < 6; ++d) {
    double s = 0;
    for (int q = 0; q < 6; ++q) s += M2[d][q] * w[q];
    quad += w[d] * s;
  }
  double bb = b1[c];
  double mean = wm / R1d + bb;
  double E2 = (quad + 2.0 * bb * wm) / R1d + bb * bb;
  double var = E2 - mean * mean;
  double sc = (double)g1[c] / sqrt(var + 1e-5);
  scale1[c] = (float)sc;
  shift1[c] = (float)((double)be1[c] - mean * sc);
}

// ---------------- W3 -> half2 K-paired pack ----------------
__global__ __launch_bounds__(256) void packw3_kernel(const float* __restrict__ W3, half2_t* __restrict__ w3h) {
  int e = blockIdx.x * 256 + threadIdx.x;   // 65536 = 64 kp x 1024 c
  int kp = e >> 10, c = e & 1023;
  float w0 = W3[(size_t)(2 * kp) * EMB + c];
  float w1 = W3[(size_t)(2 * kp + 1) * EMB + c];
  half2_t h; h[0] = (_Float16)w0; h[1] = (_Float16)w1;
  w3h[e] = h;
}

// per-node reduction table
struct NdSel { int rtA, gloA, ghiA, rtB, gloB, ghiB; };
__device__ constexpr NdSel ndtbl[8] = {
  {0, 0, 3, 1, 0, 0}, {1, 1, 3, 2, 0, 1}, {2, 2, 3, 3, 0, 2}, {3, 3, 3, 4, 0, 3},
  {5, 0, 3, 6, 0, 0}, {6, 1, 3, 7, 0, 1}, {7, 2, 3, 8, 0, 2}, {8, 3, 3, 9, 0, 3},
};

// ---------------- fused edge pass v7: pos4 gather + swizzled hp + MFMA ----------------
__global__ __launch_bounds__(256, 2) void edge2_kernel(const float4* __restrict__ pos4, const unsigned short* __restrict__ idx,
    const float* __restrict__ W1, const float* __restrict__ b1,
    const float* __restrict__ scale1, const float* __restrict__ shift1,
    const float* __restrict__ W2, const float* __restrict__ b2,
    __half2* __restrict__ am, float* __restrict__ part) {
  constexpr int TROWS = 160;              // 8 nodes x 20 edges
  __shared__ half2_t hp[TROWS * 32];      // 20 KiB  (row, k-pair, swizzled)
  __shared__ float es[TROWS * 8];         // 5 KiB (row stride 8)
  int t = threadIdx.x;
  int lane = t & 63, w = t >> 6;
  int g = lane >> 4, col16 = lane & 15;

  int jp2 = t & 31;
  float w1a[6], w1b[6];
  #pragma unroll
  for (int d = 0; d < 6; ++d) {
    w1a[d] = W1[d * C1 + 2 * jp2];
    w1b[d] = W1[d * C1 + 2 * jp2 + 1];
  }
  float b1a = b1[2 * jp2], s1a = scale1[2 * jp2], sh1a = shift1[2 * jp2];
  float b1b = b1[2 * jp2 + 1], s1b = scale1[2 * jp2 + 1], sh1b = shift1[2 * jp2 + 1];

  int wcol[2];
  wcol[0] = (w * 2 + 0) * 16 + col16;
  wcol[1] = (w * 2 + 1) * 16 + col16;
  half4_t bfr[2][4];
  float b2c[2];
  #pragma unroll
  for (int ct = 0; ct < 2; ++ct) {
    b2c[ct] = b2[wcol[ct]];
    #pragma unroll
    for (int s = 0; s < 4; ++s) {
      half4_t bf;
      #pragma unroll
      for (int i = 0; i < 4; ++i)
        bf[i] = (_Float16)W2[(s * 16 + g * 4 + i) * C2 + wcol[ct]];
      bfr[ct][s] = bf;
    }
  }
  float sums[2] = {0.f, 0.f}, sqs[2] = {0.f, 0.f};

  for (int tile = blockIdx.x; tile < NNODE / 8; tile += E2_BLOCKS) {
    if (t < TROWS) {
      int i = t;
      int e = tile * TROWS + i;
      int nd = i / 20;
      int bnode = tile * 8 + nd;
      int b = bnode >> 11, n = bnode & (NPT - 1);
      int j = idx[e];
      const float4* pb = pos4 + (size_t)b * NPT;
      float4 pn = pb[n];
      float4 pj = pb[j];
      *(float4*)&es[i * 8] = make_float4(pn.x, pn.y, pn.z, pj.x - pn.x);
      *(float2*)&es[i * 8 + 4] = make_float2(pj.y - pn.y, pj.z - pn.z);
    }
    __syncthreads();
    #pragma unroll
    for (int i = 0; i < 20; ++i) {
      int row = (t >> 5) + 8 * i;
      float4 e0 = *(const float4*)&es[row * 8];
      float2 e1 = *(const float2*)&es[row * 8 + 4];
      float a = b1a + e0.x * w1a[0] + e0.y * w1a[1] + e0.z * w1a[2]
                    + e0.w * w1a[3] + e1.x * w1a[4] + e1.y * w1a[5];
      float bvl = b1b + e0.x * w1b[0] + e0.y * w1b[1] + e0.z * w1b[2]
                      + e0.w * w1b[3] + e1.x * w1b[4] + e1.y * w1b[5];
      a = a * s1a + sh1a;   a = a > 0.f ? a : 0.f;
      bvl = bvl * s1b + sh1b; bvl = bvl > 0.f ? bvl : 0.f;
      half2_t hh; hh[0] = (_Float16)a; hh[1] = (_Float16)bvl;
      hp[row * 32 + (jp2 ^ ((row & 7) << 2))] = hh;   // swizzled store
    }
    __syncthreads();
    float4_t acc[2][10];
    #pragma unroll
    for (int ct = 0; ct < 2; ++ct)
      #pragma unroll
      for (int rt = 0; rt < 10; ++rt)
        acc[ct][rt] = (float4_t){0.f, 0.f, 0.f, 0.f};
    #pragma unroll
    for (int rt = 0; rt < 10; ++rt) {
      int arow = rt * 16 + col16;
      int sw = (arow & 7) << 2;
      half4_t afr[4];
      #pragma unroll
      for (int s = 0; s < 4; ++s)
        afr[s] = *(const half4_t*)&hp[arow * 32 + ((s * 8 + g * 2) ^ sw)];  // swizzled load
      #pragma unroll
      for (int s = 0; s < 4; ++s) {
        acc[0][rt] = __builtin_amdgcn_mfma_f32_16x16x16f16(afr[s], bfr[0][s], acc[0][rt], 0, 0, 0);
        acc[1][rt] = __builtin_amdgcn_mfma_f32_16x16x16f16(afr[s], bfr[1][s], acc[1][rt], 0, 0, 0);
      }
    }
    #pragma unroll
    for (int ct = 0; ct < 2; ++ct) {
      float m4[10], n4[10];
      float ssum = 0.f, ssq = 0.f;
      #pragma unroll
      for (int rt = 0; rt < 10; ++rt) {
        float v0 = acc[ct][rt][0] + b2c[ct];
        float v1 = acc[ct][rt][1] + b2c[ct];
        float v2 = acc[ct][rt][2] + b2c[ct];
        float v3 = acc[ct][rt][3] + b2c[ct];
        m4[rt] = fmaxf(fmaxf(v0, v1), fmaxf(v2, v3));
        n4[rt] = fminf(fminf(v0, v1), fminf(v2, v3));
        ssum += (v0 + v1) + (v2 + v3);
        ssq += v0 * v0 + v1 * v1 + v2 * v2 + v3 * v3;
      }
      sums[ct] += ssum; sqs[ct] += ssq;
      #pragma unroll
      for (int nd = 0; nd < 8; ++nd) {
        NdSel e = ndtbl[nd];
        float mv = (g >= e.gloA && g <= e.ghiA) ? m4[e.rtA] : -FLT_MAX;
        float nv = (g >= e.gloA && g <= e.ghiA) ? n4[e.rtA] : FLT_MAX;
        if (g >= e.gloB && g <= e.ghiB) {
          mv = fmaxf(mv, m4[e.rtB]);
          nv = fminf(nv, n4[e.rtB]);
        }
        #pragma unroll
        for (int off = 16; off <= 32; off <<= 1) {
          mv = fmaxf(mv, __shfl_xor(mv, off, 64));
          nv = fminf(nv, __shfl_xor(nv, off, 64));
        }
        if (g == 0) {
          int node = tile * 8 + nd;
          am[(size_t)node * C2 + wcol[ct]] = __floats2half2_rn(mv, nv);
        }
      }
    }
    __syncthreads();
  }
  #pragma unroll
  for (int ct = 0; ct < 2; ++ct) {
    float s = sums[ct], q = sqs[ct];
    #pragma unroll
    for (int off = 16; off <= 32; off <<= 1) {
      s += __shfl_xor(s, off, 64);
      q += __shfl_xor(q, off, 64);
    }
    if (g == 0) {
      part[(size_t)blockIdx.x * 256 + wcol[ct]] = s;
      part[(size_t)blockIdx.x * 256 + 128 + wcol[ct]] = q;
    }
  }
}

// ---------------- BN2 finalize ----------------
__global__ __launch_bounds__(256) void finalize2_kernel(const float* __restrict__ part,
                                 const float* __restrict__ g2w, const float* __restrict__ be2,
                                 float* __restrict__ scale2, float* __restrict__ shift2) {
  int c = blockIdx.x;   // 128
  int t = threadIdx.x;  // 256
  double s = 0, q = 0;
  for (int i = t; i < N_E2_PART; i += 256) {
    s += (double)part[(size_t)i * 256 + c];
    q += (double)part[(size_t)i * 256 + 128 + c];
  }
  __shared__ double shs[256], shq[256];
  shs[t] = s; shq[t] = q; __syncthreads();
  for (int off = 128; off > 0; off >>= 1) {
    if (t < off) { shs[t] += shs[t + off]; shq[t] += shq[t + off]; }
    __syncthreads();
  }
  if (t == 0) {
    double mean = shs[0] / R1d;
    double var = shq[0] / R1d - mean * mean;
    double sc = (double)g2w[c] / sqrt(var + 1e-5);
    scale2[c] = (float)sc;
    shift2[c] = (float)((double)be2[c] - mean * sc);
  }
}

// node value on the fly: relu(scale * (scale>=0 ? max : min) + shift)
static __device__ __forceinline__ float node_val(__half2 h2, float s, float sh) {
  float A = __low2float(h2), N = __high2float(h2);
  float v = (s >= 0.f ? A : N) * s + sh;
  return v > 0.f ? v : 0.f;
}

// ---------------- Gram partials v2: 1024 threads, 256 blocks ----------------
__global__ __launch_bounds__(1024) void gram_part_kernel(const __half2* __restrict__ am,
                                                         const float* __restrict__ scale2, const float* __restrict__ shift2,
                                                         float* __restrict__ part) {
  __shared__ float tile[64 * C2];  // 32 KiB
  __shared__ float s_s[C2], s_h[C2];
  int t = threadIdx.x;
  if (t < C2) { s_s[t] = scale2[t]; s_h[t] = shift2[t]; }
  __syncthreads();
  int i = t & 127, jh = t >> 7;    // jh in 0..7 (16 cols each)
  float acc[16];
  #pragma unroll
  for (int u = 0; u < 16; ++u) acc[u] = 0.f;
  float csum = 0.f;
  for (int tl = blockIdx.x; tl < NNODE / 64; tl += GRAM_GRID) {
    const __half2* a2 = am + (size_t)tl * 64 * C2;
    #pragma unroll
    for (int q = 0; q < 8; ++q) {
      int e = q * 1024 + t;
      int c = e & 127;
      tile[e] = node_val(a2[e], s_s[c], s_h[c]);
    }
    __syncthreads();
    #pragma unroll 4
    for (int r = 0; r < 64; ++r) {
      float xi = tile[r * C2 + i];
      const float4* row4 = (const float4*)&tile[r * C2 + jh * 16];
      #pragma unroll
      for (int u4 = 0; u4 < 4; ++u4) {
        float4 v = row4[u4];
        acc[u4 * 4 + 0] += xi * v.x;
        acc[u4 * 4 + 1] += xi * v.y;
        acc[u4 * 4 + 2] += xi * v.z;
        acc[u4 * 4 + 3] += xi * v.w;
      }
    }
    if (t < 128) {
      #pragma unroll 8
      for (int r = 0; r < 64; ++r) csum += tile[r * C2 + t];
    }
    __syncthreads();
  }
  float* pb = part + (size_t)blockIdx.x * GRAM_ELEMS;
  float4* pout = (float4*)(pb + (size_t)i * C2 + jh * 16);
  #pragma unroll
  for (int u4 = 0; u4 < 4; ++u4)
    pout[u4] = make_float4(acc[u4 * 4], acc[u4 * 4 + 1], acc[u4 * 4 + 2], acc[u4 * 4 + 3]);
  if (t < 128) pb[C2 * C2 + t] = csum;
}

// ---------------- Gram reduce ----------------
__global__ __launch_bounds__(256) void gram_reduce_kernel(const float* __restrict__ part,
                                                          double* __restrict__ G2, double* __restrict__ nodesum) {
  int e = blockIdx.x * 256 + threadIdx.x;
  if (e >= GRAM_ELEMS) return;
  double s = 0;
  for (int p = 0; p < GRAM_GRID; ++p) s += (double)part[(size_t)p * GRAM_ELEMS + e];
  if (e < C2 * C2) G2[e] = s;
  else nodesum[e - C2 * C2] = s;
}

// ---------------- BN3 coeffs from Gram ----------------
__global__ __launch_bounds__(128) void finalize3_kernel(const double* __restrict__ G2, const double* __restrict__ nodesum,
    const float* __restrict__ W3, const float* __restrict__ b3,
    const float* __restrict__ g3, const float* __restrict__ be3,
    float* __restrict__ scale3, float* __restrict__ shift3) {
  int c = blockIdx.x;   // 1024 channels
  int t = threadIdx.x;  // 128
  __shared__ double wsh[128];
  __shared__ double sh[128];
  double w = W3[(size_t)t * EMB + c];
  wsh[t] = w;
  __syncthreads();
  double rowdot = 0;
  for (int j = 0; j < 128; ++j) rowdot += G2[(size_t)j * C2 + t] * wsh[j];
  sh[t] = w * rowdot;
  __syncthreads();
  for (int off = 64; off > 0; off >>= 1) { if (t < off) sh[t] += sh[t + off]; __syncthreads(); }
  double quad = sh[0];
  __syncthreads();
  sh[t] = w * nodesum[t];
  __syncthreads();
  for (int off = 64; off > 0; off >>= 1) { if (t < off) sh[t] += sh[t + off]; __syncthreads(); }
  if (t == 0) {
    double wm = sh[0];
    double bb = b3[c];
    double mean = wm / R3d + bb;
    double E2 = (quad + 2.0 * bb * wm) / R3d + bb * bb;
    double var = E2 - mean * mean;
    double sc = (double)g3[c] / sqrt(var + 1e-5);
    scale3[c] = (float)sc;
    shift3[c] = (float)((double)be3[c] - mean * sc);
  }
}

// ---------------- linear1 apply v5: MFMA + swizzled tileh + shfl pooling ----------------
__global__ __launch_bounds__(256) void apply3pool_kernel(const __half2* __restrict__ am,
    const float* __restrict__ scale2, const float* __restrict__ shift2,
    const half2_t* __restrict__ w3h, const float* __restrict__ b3,
    const float* __restrict__ scale3, const float* __restrict__ shift3,
    float* __restrict__ pp, float* __restrict__ ps) {
  __shared__ half2_t tileh[32 * 64];  // 8 KiB (row, kp, swizzled)
  __shared__ float s_s[C2], s_h[C2];
  int rt = blockIdx.x;  // 1024 row tiles of 32 rows
  int ct = blockIdx.y;  // 2 column halves (512 each)
  int t = threadIdx.x;
  if (t < C2) { s_s[t] = scale2[t]; s_h[t] = shift2[t]; }
  __syncthreads();
  const __half2* a2 = am + (size_t)rt * 32 * C2;
  #pragma unroll
  for (int q = 0; q < 8; ++q) {
    int e = q * 256 + t;
    int row = e >> 6, kp = e & 63;
    __half2 h0 = a2[row * C2 + 2 * kp];
    __half2 h1 = a2[row * C2 + 2 * kp + 1];
    float v0 = node_val(h0, s_s[2 * kp], s_h[2 * kp]);
    float v1 = node_val(h1, s_s[2 * kp + 1], s_h[2 * kp + 1]);
    half2_t hh; hh[0] = (_Float16)v0; hh[1] = (_Float16)v1;
    tileh[row * 64 + (kp ^ ((row & 7) << 2))] = hh;   // swizzled store
  }
  __syncthreads();

  int lane = t & 63, w = t >> 6;
  int rowq = lane >> 4;
  int col16 = lane & 15;
  half4_t afr[2][8];
  #pragma unroll
  for (int rt16 = 0; rt16 < 2; ++rt16) {
    #pragma unroll
    for (int s = 0; s < 8; ++s) {
      int row = rt16 * 16 + col16;
      int jp0 = s * 8 + rowq * 2;
      afr[rt16][s] = *(const half4_t*)&tileh[row * 64 + (jp0 ^ ((row & 7) << 2))];  // swizzled load
    }
  }
  for (int ci = 0; ci < 8; ++ci) {
    int c = ct * 512 + (w * 8 + ci) * 16 + col16;   // global channel
    float4_t acc0 = {0.f, 0.f, 0.f, 0.f}, acc1 = {0.f, 0.f, 0.f, 0.f};
    #pragma unroll
    for (int s = 0; s < 8; ++s) {
      int jp0 = s * 8 + rowq * 2;
      half2_t b0 = w3h[(size_t)(jp0 + 0) * EMB + c];
      half2_t b1 = w3h[(size_t)(jp0 + 1) * EMB + c];
      half4_t bf; bf[0] = b0[0]; bf[1] = b0[1]; bf[2] = b1[0]; bf[3] = b1[1];
      acc0 = __builtin_amdgcn_mfma_f32_16x16x16f16(afr[0][s], bf, acc0, 0, 0, 0);
      acc1 = __builtin_amdgcn_mfma_f32_16x16x16f16(afr[1][s], bf, acc1, 0, 0, 0);
    }
    float b3c = b3[c], s3c = scale3[c], sh3c = shift3[c];
    float mx = 0.f, sm = 0.f;   // post-ReLU >= 0
    #pragma unroll
    for (int j = 0; j < 4; ++j) {
      float x0 = (acc0[j] + b3c) * s3c + sh3c; x0 = x0 > 0.f ? x0 : 0.f;
      float x1 = (acc1[j] + b3c) * s3c + sh3c; x1 = x1 > 0.f ? x1 : 0.f;
      mx = fmaxf(mx, fmaxf(x0, x1));
      sm += x0 + x1;
    }
    #pragma unroll
    for (int off = 16; off <= 32; off <<= 1) {
      float mo = __shfl_xor(mx, off, 64);
      float so = __shfl_xor(sm, off, 64);
      mx = fmaxf(mx, mo);
      sm += so;
    }
    if (rowq == 0) {
      pp[(size_t)rt * EMB + c] = mx;
      ps[(size_t)rt * EMB + c] = sm;
    }
  }
}

// ---------------- pool reduce ----------------
__global__ __launch_bounds__(256) void poolreduce_kernel(const float* __restrict__ pp, const float* __restrict__ ps,
                                                         float* __restrict__ pmaxo, float* __restrict__ psumo) {
  int e = blockIdx.x * 256 + threadIdx.x;  // e = b*1024 + c, grid 64
  int b = e >> 10, c = e & 1023;
  const float* bp = pp + ((size_t)b * 64) * EMB + c;
  const float* bs = ps + ((size_t)b * 64) * EMB + c;
  float mx = 0.f, sm = 0.f;
  #pragma unroll 8
  for (int tl = 0; tl < 64; ++tl) {
    float v = bp[(size_t)tl * EMB];
    float s = bs[(size_t)tl * EMB];
    mx = mx > v ? mx : v;
    sm += s;
  }
  pmaxo[e] = mx;
  psumo[e] = sm;
}

// ---------------- final linear ----------------
__global__ __launch_bounds__(64) void final_kernel(const float* __restrict__ pmax, const float* __restrict__ psum,
    const float* __restrict__ W4, const float* __restrict__ b4, float* __restrict__ out) {
  int b = blockIdx.x, t = threadIdx.x;
  #pragma unroll
  for (int o = 0; o < OUT; ++o) {
    float acc = 0.f;
    for (int tt = t; tt < 2 * EMB; tt += 64) {
      float p = (tt < EMB) ? pmax[(size_t)b * EMB + tt]
                           : psum[(size_t)b * EMB + tt - EMB] * (1.0f / (float)NPT);
      acc += p * W4[(size_t)tt * OUT + o];
    }
    #pragma unroll
    for (int off = 32; off > 0; off >>= 1) acc += __shfl_down(acc, off);
    if (t == 0) out[b * OUT + o] = acc + b4[o];
  }
}

extern "C" void kernel_launch(void* const* d_in, const int* in_sizes, int n_in,
                              void* d_out, int out_size, void* d_ws, size_t ws_size,
                              hipStream_t stream) {
  const float* pos = (const float*)d_in[0];
  const float* W1 = (const float*)d_in[1];  const float* b1 = (const float*)d_in[2];
  const float* g1 = (const float*)d_in[3];  const float* be1 = (const float*)d_in[4];
  const float* W2 = (const float*)d_in[5];  const float* b2 = (const float*)d_in[6];
  const float* g2 = (const float*)d_in[7];  const float* be2 = (const float*)d_in[8];
  const float* W3 = (const float*)d_in[9];  const float* b3 = (const float*)d_in[10];
  const float* g3 = (const float*)d_in[11]; const float* be3 = (const float*)d_in[12];
  const float* W4 = (const float*)d_in[13]; const float* b4 = (const float*)d_in[14];
  float* out = (float*)d_out;

  // ---- workspace layout, total ~34.7 MiB (35.06 MiB proven safe in round 2) ----
  char* ws = (char*)d_ws;
  unsigned short* idx = (unsigned short*)ws;               // NEDGE u16 = 1.25 MiB
  __half2* am = (__half2*)(ws + (size_t)NEDGE * 2);        // NNODE*C2 half2 = 16 MiB
  char* smallbase = (char*)(am + (size_t)NNODE * C2);

  double* dstats  = (double*)smallbase;           // 32 (27 used)
  double* G2      = dstats + 32;                  // 16384
  double* nodesum = G2 + 16384;                   // 128
  float* scale1 = (float*)(nodesum + 128);
  float* shift1 = scale1 + C1;
  float* scale2 = shift1 + C1;
  float* shift2 = scale2 + C2;
  float* scale3 = shift2 + C2;
  float* shift3 = scale3 + EMB;
  float* pooledmax = shift3 + EMB;                // 16*1024
  float* pooledsum = pooledmax + NB * EMB;        // 16*1024
  half2_t* w3h = (half2_t*)(pooledsum + NB * EMB);// 64*1024 half2 = 256 KiB
  char* scratch = (char*)(w3h + 64 * EMB);
  // lifetime-disjoint overlays on one ~16.9 MiB slab:
  float* eg_part   = (float*)scratch;             // 1024*256*4  = 1.00 MiB (edge2 -> finalize2)
  float4* pos4     = (float4*)(scratch + (2u << 20)); // 512 KiB at +2 MiB (packpos -> edge2; dead before gram_part)
  float* gram_part = (float*)scratch;             // 256*16512*4 = 16.9 MiB (gram_part -> gram_reduce)
  float* pp        = (float*)scratch;             // 1024*1024*4 = 4 MiB    (apply3pool -> poolreduce)
  float* psb       = pp + (size_t)1024 * EMB;     // 4 MiB

  hipMemsetAsync(dstats, 0, 32 * sizeof(double), stream);

  packpos_kernel<<<NNODE / 256, 256, 0, stream>>>(pos, pos4);
  knn_kernel<<<NB * NPT / 4, 256, 0, stream>>>(pos4, idx);
  packw3_kernel<<<64 * EMB / 256, 256, 0, stream>>>(W3, w3h);
  statse_kernel<<<512, 256, 0, stream>>>(pos4, idx, dstats);
  finalize1_kernel<<<1, 64, 0, stream>>>(dstats, W1, b1, g1, be1, scale1, shift1);
  edge2_kernel<<<E2_BLOCKS, 256, 0, stream>>>(pos4, idx, W1, b1, scale1, shift1, W2, b2, am, eg_part);
  finalize2_kernel<<<C2, 256, 0, stream>>>(eg_part, g2, be2, scale2, shift2);
  gram_part_kernel<<<GRAM_GRID, 1024, 0, stream>>>(am, scale2, shift2, gram_part);
  gram_reduce_kernel<<<(GRAM_ELEMS + 255) / 256, 256, 0, stream>>>(gram_part, G2, nodesum);
  finalize3_kernel<<<EMB, 128, 0, stream>>>(G2, nodesum, W3, b3, g3, be3, scale3, shift3);
  apply3pool_kernel<<<dim3(1024, 2), 256, 0, stream>>>(am, scale2, shift2, w3h, b3, scale3, shift3, pp, psb);
  poolreduce_kernel<<<NB * EMB / 256, 256, 0, stream>>>(pp, psb, pooledmax, pooledsum);
  final_kernel<<<NB, 64, 0, stream>>>(pooledmax, pooledsum, W4, b4, out);
}

// Round 20
// 287.076 us; speedup vs baseline: 1.0879x; 1.0879x over previous
//
#include <hip/hip_runtime.h>
#include <hip/hip_fp16.h>
#include <float.h>

// ---- fixed problem shape ----
constexpr int NB  = 16;     // batch (clouds)
constexpr int NPT = 2048;   // points per cloud
constexpr int KK  = 20;     // kNN
constexpr int NEDGE = NB * NPT * KK;       // 655360
constexpr int C1 = 64, C2 = 128, EMB = 1024, OUT = 7;
constexpr int NNODE = NB * NPT;            // 32768
constexpr int E2_BLOCKS = 1024;            // edge2 grid (4 tiles each)
constexpr int N_E2_PART = 1024;            // edge2 stat partials (1 per block)
constexpr int GRAM_GRID = 256;             // one block per CU, 2 tiles each
constexpr int GRAM_ELEMS = C2 * C2 + C2;   // 16512 (Gram + colsum)
__device__ constexpr double R1d = (double)NEDGE;       // BN1/BN2 row count
__device__ constexpr double R3d = (double)(NB * NPT);  // BN3 row count

using half2_t = _Float16 __attribute__((ext_vector_type(2)));
using half4_t = _Float16 __attribute__((ext_vector_type(4)));
using float4_t = float __attribute__((ext_vector_type(4)));

static __device__ __forceinline__ unsigned long long ullmin2(unsigned long long a, unsigned long long b) {
  return a < b ? a : b;
}

// ---------------- kNN v10: raw-pos loads (r18 register footprint) + u32 bound stage ----------------
// r19 lesson: pos4 float4 loads pushed VGPR 64->80 -> occupancy 40->31% -> slower.
// This keeps r18's scalar loads (VGPR 64) and only swaps the bound stage to u32:
// running umin32 of dist-bits during key build (replaces 31-op u64 min tree), u32
// bitonic of the 64 lane-mins (1 bpermute/step vs 2). d20 = 20th smallest lane-min
// dist-bits; survivors = {key : distbits <= d20} is a superset of the top-20
// (the 20 smallest lane-mins are distinct keys with distbits <= d20).
// Survivor selection stays exact u64 (full (dist,idx) order = jax.lax.top_k ties).
__global__ __launch_bounds__(256) void knn_kernel(const float* __restrict__ pos, unsigned short* __restrict__ idxo) {
  __shared__ unsigned long long surv[4][128];   // 4 KiB
  int t = threadIdx.x;
  int lane = t & 63, w = t >> 6;
  int bn = blockIdx.x * 4 + w;            // 8192 blocks x 4 waves = 32768 queries
  int b = bn >> 11, n = bn & (NPT - 1);
  const float* pb = pos + (size_t)b * NPT * 3;
  float xn = pb[n * 3], yn = pb[n * 3 + 1], zn = pb[n * 3 + 2];
  float sqn = xn * xn + yn * yn + zn * zn;

  unsigned long long key[32];
  unsigned dmin = 0xffffffffu;
  #pragma unroll
  for (int i = 0; i < 32; ++i) {
    int m = i * 64 + lane;
    float xm = pb[m * 3], ym = pb[m * 3 + 1], zm = pb[m * 3 + 2];
    float sqm = xm * xm + ym * ym + zm * zm;
    float dt = xn * xm + yn * ym + zn * zm;
    float d = sqn + sqm - 2.0f * dt;
    unsigned ub = __float_as_uint(d);
    ub = (ub & 0x80000000u) ? ~ub : (ub | 0x80000000u);  // order-preserving map
    key[i] = ((unsigned long long)ub << 32) | (unsigned long long)(unsigned)m;
    dmin = dmin < ub ? dmin : ub;
  }

  // bitonic sort of the 64 lane-min dist-bits (u32, ascending by lane)
  unsigned v = dmin;
  #pragma unroll
  for (int k = 2; k <= 64; k <<= 1) {
    #pragma unroll
    for (int j = k >> 1; j > 0; j >>= 1) {
      unsigned o = (unsigned)__shfl_xor((int)v, j, 64);
      bool up = ((lane & k) == 0);
      bool lower = ((lane & j) == 0);
      unsigned mn = v < o ? v : o;
      unsigned mx = v < o ? o : v;
      v = (lower == up) ? mn : mx;
    }
  }
  unsigned d20 = (unsigned)__shfl((int)v, 19, 64);  // 20th smallest lane-min dist-bits

  // compact survivors (distbits <= d20) into LDS
  unsigned long long* sv = surv[w];
  unsigned total = 0;
  #pragma unroll
  for (int i = 0; i < 32; ++i) {
    bool p = (unsigned)(key[i] >> 32) <= d20;
    unsigned long long mask = __ballot(p);
    unsigned pre = __builtin_amdgcn_mbcnt_hi((unsigned)(mask >> 32),
                   __builtin_amdgcn_mbcnt_lo((unsigned)mask, 0));
    unsigned posi = total + pre;
    if (p && posi < 128u) sv[posi] = key[i];
    total += (unsigned)__popcll(mask);
  }

  if (total <= 64u) {
    // fast path: one u64 bitonic sort of <=64 survivors (INF-padded)
    unsigned long long s = (lane < (int)total) ? sv[lane] : ~0ull;
    #pragma unroll
    for (int k = 2; k <= 64; k <<= 1) {
      #pragma unroll
      for (int j = k >> 1; j > 0; j >>= 1) {
        unsigned long long o = (unsigned long long)__shfl_xor((long long)s, j, 64);
        bool up = ((lane & k) == 0);
        bool lower = ((lane & j) == 0);
        unsigned long long mn = s < o ? s : o;
        unsigned long long mx = s < o ? o : s;
        s = (lower == up) ? mn : mx;
      }
    }
    if (lane < KK) idxo[(size_t)bn * KK + lane] = (unsigned short)(unsigned)(s & 0xffffffffull);
    return;
  }

  unsigned long long T = 0;
  int myidx = 0;
  if (total <= 128u) {
    unsigned long long s0 = (lane < (int)total) ? sv[lane] : ~0ull;
    unsigned long long s1 = (lane + 64 < (int)total) ? sv[lane + 64] : ~0ull;
    for (int r = 0; r < KK; ++r) {
      unsigned long long best = ullmin2(s0 - T, s1 - T);  // consumed (<T) wrap high
      #pragma unroll
      for (int off = 32; off > 0; off >>= 1) {
        unsigned long long o = (unsigned long long)__shfl_xor((long long)best, off, 64);
        best = ullmin2(best, o);
      }
      unsigned long long winner = best + T;
      if (lane == r) myidx = (int)(unsigned)(winner & 0xffffffffull);
      T = winner + 1;
    }
  } else {
    for (int r = 0; r < KK; ++r) {
      unsigned long long u0[16];
      #pragma unroll
      for (int i = 0; i < 16; ++i)
        u0[i] = ullmin2(key[2 * i] - T, key[2 * i + 1] - T);
      #pragma unroll
      for (int s = 8; s > 0; s >>= 1)
        #pragma unroll
        for (int i = 0; i < 8; ++i)
          if (i < s) u0[i] = ullmin2(u0[i], u0[i + s]);
      unsigned long long best = u0[0];
      #pragma unroll
      for (int off = 32; off > 0; off >>= 1) {
        unsigned long long o = (unsigned long long)__shfl_xor((long long)best, off, 64);
        best = ullmin2(best, o);
      }
      unsigned long long winner = best + T;
      if (lane == r) myidx = (int)(unsigned)(winner & 0xffffffffull);
      T = winner + 1;
    }
  }
  if (lane < KK) idxo[(size_t)bn * KK + lane] = (unsigned short)(unsigned)myidx;
}

// ---------------- edge-feature first/second moments (6 + 21 doubles) ----------------
__global__ __launch_bounds__(256) void statse_kernel(const float* __restrict__ pos, const unsigned short* __restrict__ idx,
                                                     double* __restrict__ dstats) {
  float acc[27];
  #pragma unroll
  for (int i = 0; i < 27; ++i) acc[i] = 0.f;
  int t = threadIdx.x;
  for (int e = blockIdx.x * 256 + t; e < NEDGE; e += gridDim.x * 256) {
    int bn = e / KK;
    int b = bn >> 11, n = bn & (NPT - 1);
    int j = idx[e];
    const float* pb = pos + (size_t)b * NPT * 3;
    float f[6];
    f[0] = pb[n * 3]; f[1] = pb[n * 3 + 1]; f[2] = pb[n * 3 + 2];
    f[3] = pb[j * 3] - f[0]; f[4] = pb[j * 3 + 1] - f[1]; f[5] = pb[j * 3 + 2] - f[2];
    int p = 6;
    #pragma unroll
    for (int d = 0; d < 6; ++d) acc[d] += f[d];
    #pragma unroll
    for (int d = 0; d < 6; ++d)
      #pragma unroll
      for (int q = d; q < 6; ++q) { acc[p] += f[d] * f[q]; ++p; }
  }
  __shared__ float sred[4][27];
  int lane = t & 63, w = t >> 6;
  #pragma unroll
  for (int c = 0; c < 27; ++c) {
    float v = acc[c];
    #pragma unroll
    for (int off = 32; off > 0; off >>= 1) v += __shfl_down(v, off);
    if (lane == 0) sred[w][c] = v;
  }
  __syncthreads();
  if (t < 27) {
    double s = (double)sred[0][t] + (double)sred[1][t] + (double)sred[2][t] + (double)sred[3][t];
    atomicAdd(&dstats[t], s);
  }
}

// ---------------- BN1 coeffs from moments ----------------
__global__ void finalize1_kernel(const double* __restrict__ dstats, const float* __restrict__ W1,
                                 const float* __restrict__ b1, const float* __restrict__ g1,
                                 const float* __restrict__ be1, float* __restrict__ scale1,
                                 float* __restrict__ shift1) {
  int c = threadIdx.x;  // 64
  double m1[6], M2[6][6];
  for (int d = 0; d < 6; ++d) m1[d] = dstats[d];
  int p = 6;
  for (int d = 0; d < 6; ++d)
    for (int q = d; q < 6; ++q) { M2[d][q] = dstats[p]; M2[q][d] = dstats[p]; ++p; }
  double w[6];
  for (int d = 0; d < 6; ++d) w[d] = W1[d * C1 + c];
  double wm = 0, quad = 0;
  for (int d = 0; d < 6; ++d) wm += w[d] * m1[d];
  for (int d = 0; d < 6; ++d) {
    double s = 0;
    for (int q = 0; q < 6; ++q) s += M2[d][q] * w[q];
    quad += w[d] * s;
  }
  double bb = b1[c];
  double mean = wm / R1d + bb;
  double E2 = (quad + 2.0 * bb * wm) / R1d + bb * bb;
  double var = E2 - mean * mean;
  double sc = (double)g1[c] / sqrt(var + 1e-5);
  scale1[c] = (float)sc;
  shift1[c] = (float)((double)be1[c] - mean * sc);
}

// ---------------- W3 -> half2 K-paired pack ----------------
__global__ __launch_bounds__(256) void packw3_kernel(const float* __restrict__ W3, half2_t* __restrict__ w3h) {
  int e = blockIdx.x * 256 + threadIdx.x;   // 65536 = 64 kp x 1024 c
  int kp = e >> 10, c = e & 1023;
  float w0 = W3[(size_t)(2 * kp) * EMB + c];
  float w1 = W3[(size_t)(2 * kp + 1) * EMB + c];
  half2_t h; h[0] = (_Float16)w0; h[1] = (_Float16)w1;
  w3h[e] = h;
}

// per-node reduction table
struct NdSel { int rtA, gloA, ghiA, rtB, gloB, ghiB; };
__device__ constexpr NdSel ndtbl[8] = {
  {0, 0, 3, 1, 0, 0}, {1, 1, 3, 2, 0, 1}, {2, 2, 3, 3, 0, 2}, {3, 3, 3, 4, 0, 3},
  {5, 0, 3, 6, 0, 0}, {6, 1, 3, 7, 0, 1}, {7, 2, 3, 8, 0, 2}, {8, 3, 3, 9, 0, 3},
};

// ---------------- fused edge pass v6: XOR-swizzled hp + MFMA (r18 form) ----------------
__global__ __launch_bounds__(256, 2) void edge2_kernel(const float* __restrict__ pos, const unsigned short* __restrict__ idx,
    const float* __restrict__ W1, const float* __restrict__ b1,
    const float* __restrict__ scale1, const float* __restrict__ shift1,
    const float* __restrict__ W2, const float* __restrict__ b2,
    __half2* __restrict__ am, float* __restrict__ part) {
  constexpr int TROWS = 160;              // 8 nodes x 20 edges
  __shared__ half2_t hp[TROWS * 32];      // 20 KiB  (row, k-pair, swizzled)
  __shared__ float es[TROWS * 8];         // 5 KiB (row stride 8)
  int t = threadIdx.x;
  int lane = t & 63, w = t >> 6;
  int g = lane >> 4, col16 = lane & 15;

  int jp2 = t & 31;
  float w1a[6], w1b[6];
  #pragma unroll
  for (int d = 0; d < 6; ++d) {
    w1a[d] = W1[d * C1 + 2 * jp2];
    w1b[d] = W1[d * C1 + 2 * jp2 + 1];
  }
  float b1a = b1[2 * jp2], s1a = scale1[2 * jp2], sh1a = shift1[2 * jp2];
  float b1b = b1[2 * jp2 + 1], s1b = scale1[2 * jp2 + 1], sh1b = shift1[2 * jp2 + 1];

  int wcol[2];
  wcol[0] = (w * 2 + 0) * 16 + col16;
  wcol[1] = (w * 2 + 1) * 16 + col16;
  half4_t bfr[2][4];
  float b2c[2];
  #pragma unroll
  for (int ct = 0; ct < 2; ++ct) {
    b2c[ct] = b2[wcol[ct]];
    #pragma unroll
    for (int s = 0; s < 4; ++s) {
      half4_t bf;
      #pragma unroll
      for (int i = 0; i < 4; ++i)
        bf[i] = (_Float16)W2[(s * 16 + g * 4 + i) * C2 + wcol[ct]];
      bfr[ct][s] = bf;
    }
  }
  float sums[2] = {0.f, 0.f}, sqs[2] = {0.f, 0.f};

  for (int tile = blockIdx.x; tile < NNODE / 8; tile += E2_BLOCKS) {
    if (t < TROWS) {
      int i = t;
      int e = tile * TROWS + i;
      int nd = i / 20;
      int bnode = tile * 8 + nd;
      int b = bnode >> 11, n = bnode & (NPT - 1);
      int j = idx[e];
      const float* pb = pos + (size_t)b * NPT * 3;
      float xi0 = pb[n * 3], xi1 = pb[n * 3 + 1], xi2 = pb[n * 3 + 2];
      float xj0 = pb[j * 3], xj1 = pb[j * 3 + 1], xj2 = pb[j * 3 + 2];
      *(float4*)&es[i * 8] = make_float4(xi0, xi1, xi2, xj0 - xi0);
      *(float2*)&es[i * 8 + 4] = make_float2(xj1 - xi1, xj2 - xi2);
    }
    __syncthreads();
    #pragma unroll
    for (int i = 0; i < 20; ++i) {
      int row = (t >> 5) + 8 * i;
      float4 e0 = *(const float4*)&es[row * 8];
      float2 e1 = *(const float2*)&es[row * 8 + 4];
      float a = b1a + e0.x * w1a[0] + e0.y * w1a[1] + e0.z * w1a[2]
                    + e0.w * w1a[3] + e1.x * w1a[4] + e1.y * w1a[5];
      float bvl = b1b + e0.x * w1b[0] + e0.y * w1b[1] + e0.z * w1b[2]
                      + e0.w * w1b[3] + e1.x * w1b[4] + e1.y * w1b[5];
      a = a * s1a + sh1a;   a = a > 0.f ? a : 0.f;
      bvl = bvl * s1b + sh1b; bvl = bvl > 0.f ? bvl : 0.f;
      half2_t hh; hh[0] = (_Float16)a; hh[1] = (_Float16)bvl;
      hp[row * 32 + (jp2 ^ ((row & 7) << 2))] = hh;   // swizzled store
    }
    __syncthreads();
    float4_t acc[2][10];
    #pragma unroll
    for (int ct = 0; ct < 2; ++ct)
      #pragma unroll
      for (int rt = 0; rt < 10; ++rt)
        acc[ct][rt] = (float4_t){0.f, 0.f, 0.f, 0.f};
    #pragma unroll
    for (int rt = 0; rt < 10; ++rt) {
      int arow = rt * 16 + col16;
      int sw = (arow & 7) << 2;
      half4_t afr[4];
      #pragma unroll
      for (int s = 0; s < 4; ++s)
        afr[s] = *(const half4_t*)&hp[arow * 32 + ((s * 8 + g * 2) ^ sw)];  // swizzled load
      #pragma unroll
      for (int s = 0; s < 4; ++s) {
        acc[0][rt] = __builtin_amdgcn_mfma_f32_16x16x16f16(afr[s], bfr[0][s], acc[0][rt], 0, 0, 0);
        acc[1][rt] = __builtin_amdgcn_mfma_f32_16x16x16f16(afr[s], bfr[1][s], acc[1][rt], 0, 0, 0);
      }
    }
    #pragma unroll
    for (int ct = 0; ct < 2; ++ct) {
      float m4[10], n4[10];
      float ssum = 0.f, ssq = 0.f;
      #pragma unroll
      for (int rt = 0; rt < 10; ++rt) {
        float v0 = acc[ct][rt][0] + b2c[ct];
        float v1 = acc[ct][rt][1] + b2c[ct];
        float v2 = acc[ct][rt][2] + b2c[ct];
        float v3 = acc[ct][rt][3] + b2c[ct];
        m4[rt] = fmaxf(fmaxf(v0, v1), fmaxf(v2, v3));
        n4[rt] = fminf(fminf(v0, v1), fminf(v2, v3));
        ssum += (v0 + v1) + (v2 + v3);
        ssq += v0 * v0 + v1 * v1 + v2 * v2 + v3 * v3;
      }
      sums[ct] += ssum; sqs[ct] += ssq;
      #pragma unroll
      for (int nd = 0; nd < 8; ++nd) {
        NdSel e = ndtbl[nd];
        float mv = (g >= e.gloA && g <= e.ghiA) ? m4[e.rtA] : -FLT_MAX;
        float nv = (g >= e.gloA && g <= e.ghiA) ? n4[e.rtA] : FLT_MAX;
        if (g >= e.gloB && g <= e.ghiB) {
          mv = fmaxf(mv, m4[e.rtB]);
          nv = fminf(nv, n4[e.rtB]);
        }
        #pragma unroll
        for (int off = 16; off <= 32; off <<= 1) {
          mv = fmaxf(mv, __shfl_xor(mv, off, 64));
          nv = fminf(nv, __shfl_xor(nv, off, 64));
        }
        if (g == 0) {
          int node = tile * 8 + nd;
          am[(size_t)node * C2 + wcol[ct]] = __floats2half2_rn(mv, nv);
        }
      }
    }
    __syncthreads();
  }
  #pragma unroll
  for (int ct = 0; ct < 2; ++ct) {
    float s = sums[ct], q = sqs[ct];
    #pragma unroll
    for (int off = 16; off <= 32; off <<= 1) {
      s += __shfl_xor(s, off, 64);
      q += __shfl_xor(q, off, 64);
    }
    if (g == 0) {
      part[(size_t)blockIdx.x * 256 + wcol[ct]] = s;
      part[(size_t)blockIdx.x * 256 + 128 + wcol[ct]] = q;
    }
  }
}

// ---------------- BN2 finalize ----------------
__global__ __launch_bounds__(256) void finalize2_kernel(const float* __restrict__ part,
                                 const float* __restrict__ g2w, const float* __restrict__ be2,
                                 float* __restrict__ scale2, float* __restrict__ shift2) {
  int c = blockIdx.x;   // 128
  int t = threadIdx.x;  // 256
  double s = 0, q = 0;
  for (int i = t; i < N_E2_PART; i += 256) {
    s += (double)part[(size_t)i * 256 + c];
    q += (double)part[(size_t)i * 256 + 128 + c];
  }
  __shared__ double shs[256], shq[256];
  shs[t] = s; shq[t] = q; __syncthreads();
  for (int off = 128; off > 0; off >>= 1) {
    if (t < off) { shs[t] += shs[t + off]; shq[t] += shq[t + off]; }
    __syncthreads();
  }
  if (t == 0) {
    double mean = shs[0] / R1d;
    double var = shq[0] / R1d - mean * mean;
    double sc = (double)g2w[c] / sqrt(var + 1e-5);
    scale2[c] = (float)sc;
    shift2[c] = (float)((double)be2[c] - mean * sc);
  }
}

// node value on the fly: relu(scale * (scale>=0 ? max : min) + shift)
static __device__ __forceinline__ float node_val(__half2 h2, float s, float sh) {
  float A = __low2float(h2), N = __high2float(h2);
  float v = (s >= 0.f ? A : N) * s + sh;
  return v > 0.f ? v : 0.f;
}

// ---------------- Gram partials v2: 1024 threads, 256 blocks ----------------
__global__ __launch_bounds__(1024) void gram_part_kernel(const __half2* __restrict__ am,
                                                         const float* __restrict__ scale2, const float* __restrict__ shift2,
                                                         float* __restrict__ part) {
  __shared__ float tile[64 * C2];  // 32 KiB
  __shared__ float s_s[C2], s_h[C2];
  int t = threadIdx.x;
  if (t < C2) { s_s[t] = scale2[t]; s_h[t] = shift2[t]; }
  __syncthreads();
  int i = t & 127, jh = t >> 7;    // jh in 0..7 (16 cols each)
  float acc[16];
  #pragma unroll
  for (int u = 0; u < 16; ++u) acc[u] = 0.f;
  float csum = 0.f;
  for (int tl = blockIdx.x; tl < NNODE / 64; tl += GRAM_GRID) {
    const __half2* a2 = am + (size_t)tl * 64 * C2;
    #pragma unroll
    for (int q = 0; q < 8; ++q) {
      int e = q * 1024 + t;
      int c = e & 127;
      tile[e] = node_val(a2[e], s_s[c], s_h[c]);
    }
    __syncthreads();
    #pragma unroll 4
    for (int r = 0; r < 64; ++r) {
      float xi = tile[r * C2 + i];
      const float4* row4 = (const float4*)&tile[r * C2 + jh * 16];
      #pragma unroll
      for (int u4 = 0; u4 < 4; ++u4) {
        float4 v = row4[u4];
        acc[u4 * 4 + 0] += xi * v.x;
        acc[u4 * 4 + 1] += xi * v.y;
        acc[u4 * 4 + 2] += xi * v.z;
        acc[u4 * 4 + 3] += xi * v.w;
      }
    }
    if (t < 128) {
      #pragma unroll 8
      for (int r = 0; r < 64; ++r) csum += tile[r * C2 + t];
    }
    __syncthreads();
  }
  float* pb = part + (size_t)blockIdx.x * GRAM_ELEMS;
  float4* pout = (float4*)(pb + (size_t)i * C2 + jh * 16);
  #pragma unroll
  for (int u4 = 0; u4 < 4; ++u4)
    pout[u4] = make_float4(acc[u4 * 4], acc[u4 * 4 + 1], acc[u4 * 4 + 2], acc[u4 * 4 + 3]);
  if (t < 128) pb[C2 * C2 + t] = csum;
}

// ---------------- Gram reduce ----------------
__global__ __launch_bounds__(256) void gram_reduce_kernel(const float* __restrict__ part,
                                                          double* __restrict__ G2, double* __restrict__ nodesum) {
  int e = blockIdx.x * 256 + threadIdx.x;
  if (e >= GRAM_ELEMS) return;
  double s = 0;
  for (int p = 0; p < GRAM_GRID; ++p) s += (double)part[(size_t)p * GRAM_ELEMS + e];
  if (e < C2 * C2) G2[e] = s;
  else nodesum[e - C2 * C2] = s;
}

// ---------------- BN3 coeffs from Gram ----------------
__global__ __launch_bounds__(128) void finalize3_kernel(const double* __restrict__ G2, const double* __restrict__ nodesum,
    const float* __restrict__ W3, const float* __restrict__ b3,
    const float* __restrict__ g3, const float* __restrict__ be3,
    float* __restrict__ scale3, float* __restrict__ shift3) {
  int c = blockIdx.x;   // 1024 channels
  int t = threadIdx.x;  // 128
  __shared__ double wsh[128];
  __shared__ double sh[128];
  double w = W3[(size_t)t * EMB + c];
  wsh[t] = w;
  __syncthreads();
  double rowdot = 0;
  for (int j = 0; j < 128; ++j) rowdot += G2[(size_t)j * C2 + t] * wsh[j];
  sh[t] = w * rowdot;
  __syncthreads();
  for (int off = 64; off > 0; off >>= 1) { if (t < off) sh[t] += sh[t + off]; __syncthreads(); }
  double quad = sh[0];
  __syncthreads();
  sh[t] = w * nodesum[t];
  __syncthreads();
  for (int off = 64; off > 0; off >>= 1) { if (t < off) sh[t] += sh[t + off]; __syncthreads(); }
  if (t == 0) {
    double wm = sh[0];
    double bb = b3[c];
    double mean = wm / R3d + bb;
    double E2 = (quad + 2.0 * bb * wm) / R3d + bb * bb;
    double var = E2 - mean * mean;
    double sc = (double)g3[c] / sqrt(var + 1e-5);
    scale3[c] = (float)sc;
    shift3[c] = (float)((double)be3[c] - mean * sc);
  }
}

// ---------------- linear1 apply v5: MFMA + swizzled tileh + shfl pooling ----------------
__global__ __launch_bounds__(256) void apply3pool_kernel(const __half2* __restrict__ am,
    const float* __restrict__ scale2, const float* __restrict__ shift2,
    const half2_t* __restrict__ w3h, const float* __restrict__ b3,
    const float* __restrict__ scale3, const float* __restrict__ shift3,
    float* __restrict__ pp, float* __restrict__ ps) {
  __shared__ half2_t tileh[32 * 64];  // 8 KiB (row, kp, swizzled)
  __shared__ float s_s[C2], s_h[C2];
  int rt = blockIdx.x;  // 1024 row tiles of 32 rows
  int ct = blockIdx.y;  // 2 column halves (512 each)
  int t = threadIdx.x;
  if (t < C2) { s_s[t] = scale2[t]; s_h[t] = shift2[t]; }
  __syncthreads();
  const __half2* a2 = am + (size_t)rt * 32 * C2;
  #pragma unroll
  for (int q = 0; q < 8; ++q) {
    int e = q * 256 + t;
    int row = e >> 6, kp = e & 63;
    __half2 h0 = a2[row * C2 + 2 * kp];
    __half2 h1 = a2[row * C2 + 2 * kp + 1];
    float v0 = node_val(h0, s_s[2 * kp], s_h[2 * kp]);
    float v1 = node_val(h1, s_s[2 * kp + 1], s_h[2 * kp + 1]);
    half2_t hh; hh[0] = (_Float16)v0; hh[1] = (_Float16)v1;
    tileh[row * 64 + (kp ^ ((row & 7) << 2))] = hh;   // swizzled store
  }
  __syncthreads();

  int lane = t & 63, w = t >> 6;
  int rowq = lane >> 4;
  int col16 = lane & 15;
  half4_t afr[2][8];
  #pragma unroll
  for (int rt16 = 0; rt16 < 2; ++rt16) {
    #pragma unroll
    for (int s = 0; s < 8; ++s) {
      int row = rt16 * 16 + col16;
      int jp0 = s * 8 + rowq * 2;
      afr[rt16][s] = *(const half4_t*)&tileh[row * 64 + (jp0 ^ ((row & 7) << 2))];  // swizzled load
    }
  }
  for (int ci = 0; ci < 8; ++ci) {
    int c = ct * 512 + (w * 8 + ci) * 16 + col16;   // global channel
    float4_t acc0 = {0.f, 0.f, 0.f, 0.f}, acc1 = {0.f, 0.f, 0.f, 0.f};
    #pragma unroll
    for (int s = 0; s < 8; ++s) {
      int jp0 = s * 8 + rowq * 2;
      half2_t b0 = w3h[(size_t)(jp0 + 0) * EMB + c];
      half2_t b1 = w3h[(size_t)(jp0 + 1) * EMB + c];
      half4_t bf; bf[0] = b0[0]; bf[1] = b0[1]; bf[2] = b1[0]; bf[3] = b1[1];
      acc0 = __builtin_amdgcn_mfma_f32_16x16x16f16(afr[0][s], bf, acc0, 0, 0, 0);
      acc1 = __builtin_amdgcn_mfma_f32_16x16x16f16(afr[1][s], bf, acc1, 0, 0, 0);
    }
    float b3c = b3[c], s3c = scale3[c], sh3c = shift3[c];
    float mx = 0.f, sm = 0.f;   // post-ReLU >= 0
    #pragma unroll
    for (int j = 0; j < 4; ++j) {
      float x0 = (acc0[j] + b3c) * s3c + sh3c; x0 = x0 > 0.f ? x0 : 0.f;
      float x1 = (acc1[j] + b3c) * s3c + sh3c; x1 = x1 > 0.f ? x1 : 0.f;
      mx = fmaxf(mx, fmaxf(x0, x1));
      sm += x0 + x1;
    }
    #pragma unroll
    for (int off = 16; off <= 32; off <<= 1) {
      float mo = __shfl_xor(mx, off, 64);
      float so = __shfl_xor(sm, off, 64);
      mx = fmaxf(mx, mo);
      sm += so;
    }
    if (rowq == 0) {
      pp[(size_t)rt * EMB + c] = mx;
      ps[(size_t)rt * EMB + c] = sm;
    }
  }
}

// ---------------- pool reduce ----------------
__global__ __launch_bounds__(256) void poolreduce_kernel(const float* __restrict__ pp, const float* __restrict__ ps,
                                                         float* __restrict__ pmaxo, float* __restrict__ psumo) {
  int e = blockIdx.x * 256 + threadIdx.x;  // e = b*1024 + c, grid 64
  int b = e >> 10, c = e & 1023;
  const float* bp = pp + ((size_t)b * 64) * EMB + c;
  const float* bs = ps + ((size_t)b * 64) * EMB + c;
  float mx = 0.f, sm = 0.f;
  #pragma unroll 8
  for (int tl = 0; tl < 64; ++tl) {
    float v = bp[(size_t)tl * EMB];
    float s = bs[(size_t)tl * EMB];
    mx = mx > v ? mx : v;
    sm += s;
  }
  pmaxo[e] = mx;
  psumo[e] = sm;
}

// ---------------- final linear ----------------
__global__ __launch_bounds__(64) void final_kernel(const float* __restrict__ pmax, const float* __restrict__ psum,
    const float* __restrict__ W4, const float* __restrict__ b4, float* __restrict__ out) {
  int b = blockIdx.x, t = threadIdx.x;
  #pragma unroll
  for (int o = 0; o < OUT; ++o) {
    float acc = 0.f;
    for (int tt = t; tt < 2 * EMB; tt += 64) {
      float p = (tt < EMB) ? pmax[(size_t)b * EMB + tt]
                           : psum[(size_t)b * EMB + tt - EMB] * (1.0f / (float)NPT);
      acc += p * W4[(size_t)tt * OUT + o];
    }
    #pragma unroll
    for (int off = 32; off > 0; off >>= 1) acc += __shfl_down(acc, off);
    if (t == 0) out[b * OUT + o] = acc + b4[o];
  }
}

extern "C" void kernel_launch(void* const* d_in, const int* in_sizes, int n_in,
                              void* d_out, int out_size, void* d_ws, size_t ws_size,
                              hipStream_t stream) {
  const float* pos = (const float*)d_in[0];
  const float* W1 = (const float*)d_in[1];  const float* b1 = (const float*)d_in[2];
  const float* g1 = (const float*)d_in[3];  const float* be1 = (const float*)d_in[4];
  const float* W2 = (const float*)d_in[5];  const float* b2 = (const float*)d_in[6];
  const float* g2 = (const float*)d_in[7];  const float* be2 = (const float*)d_in[8];
  const float* W3 = (const float*)d_in[9];  const float* b3 = (const float*)d_in[10];
  const float* g3 = (const float*)d_in[11]; const float* be3 = (const float*)d_in[12];
  const float* W4 = (const float*)d_in[13]; const float* b4 = (const float*)d_in[14];
  float* out = (float*)d_out;

  // ---- workspace layout, total ~34.7 MiB (35.06 MiB proven safe in round 2) ----
  char* ws = (char*)d_ws;
  unsigned short* idx = (unsigned short*)ws;               // NEDGE u16 = 1.25 MiB
  __half2* am = (__half2*)(ws + (size_t)NEDGE * 2);        // NNODE*C2 half2 = 16 MiB
  char* smallbase = (char*)(am + (size_t)NNODE * C2);

  double* dstats  = (double*)smallbase;           // 32 (27 used)
  double* G2      = dstats + 32;                  // 16384
  double* nodesum = G2 + 16384;                   // 128
  float* scale1 = (float*)(nodesum + 128);
  float* shift1 = scale1 + C1;
  float* scale2 = shift1 + C1;
  float* shift2 = scale2 + C2;
  float* scale3 = shift2 + C2;
  float* shift3 = scale3 + EMB;
  float* pooledmax = shift3 + EMB;                // 16*1024
  float* pooledsum = pooledmax + NB * EMB;        // 16*1024
  half2_t* w3h = (half2_t*)(pooledsum + NB * EMB);// 64*1024 half2 = 256 KiB
  char* scratch = (char*)(w3h + 64 * EMB);
  // lifetime-disjoint overlays on one ~16.9 MiB slab:
  float* eg_part   = (float*)scratch;             // 1024*256*4  = 1.00 MiB (edge2 -> finalize2)
  float* gram_part = (float*)scratch;             // 256*16512*4 = 16.9 MiB (gram_part -> gram_reduce)
  float* pp        = (float*)scratch;             // 1024*1024*4 = 4 MiB    (apply3pool -> poolreduce)
  float* psb       = pp + (size_t)1024 * EMB;     // 4 MiB

  hipMemsetAsync(dstats, 0, 32 * sizeof(double), stream);

  knn_kernel<<<NB * NPT / 4, 256, 0, stream>>>(pos, idx);
  packw3_kernel<<<64 * EMB / 256, 256, 0, stream>>>(W3, w3h);
  statse_kernel<<<512, 256, 0, stream>>>(pos, idx, dstats);
  finalize1_kernel<<<1, 64, 0, stream>>>(dstats, W1, b1, g1, be1, scale1, shift1);
  edge2_kernel<<<E2_BLOCKS, 256, 0, stream>>>(pos, idx, W1, b1, scale1, shift1, W2, b2, am, eg_part);
  finalize2_kernel<<<C2, 256, 0, stream>>>(eg_part, g2, be2, scale2, shift2);
  gram_part_kernel<<<GRAM_GRID, 1024, 0, stream>>>(am, scale2, shift2, gram_part);
  gram_reduce_kernel<<<(GRAM_ELEMS + 255) / 256, 256, 0, stream>>>(gram_part, G2, nodesum);
  finalize3_kernel<<<EMB, 128, 0, stream>>>(G2, nodesum, W3, b3, g3, be3, scale3, shift3);
  apply3pool_kernel<<<dim3(1024, 2), 256, 0, stream>>>(am, scale2, shift2, w3h, b3, scale3, shift3, pp, psb);
  poolreduce_kernel<<<NB * EMB / 256, 256, 0, stream>>>(pp, psb, pooledmax, pooledsum);
  final_kernel<<<NB, 64, 0, stream>>>(pooledmax, pooledsum, W4, b4, out);
}

// Round 21
// 283.527 us; speedup vs baseline: 1.1015x; 1.0125x over previous
//
#include <hip/hip_runtime.h>
#include <hip/hip_fp16.h>
#include <float.h>

// ---- fixed problem shape ----
constexpr int NB  = 16;     // batch (clouds)
constexpr int NPT = 2048;   // points per cloud
constexpr int KK  = 20;     // kNN
constexpr int NEDGE = NB * NPT * KK;       // 655360
constexpr int C1 = 64, C2 = 128, EMB = 1024, OUT = 7;
constexpr int NNODE = NB * NPT;            // 32768
constexpr int E2_BLOCKS = 1024;            // edge2 grid (4 tiles each)
constexpr int N_E2_PART = 1024;            // edge2 stat partials (1 per block)
constexpr int GRAM_GRID = 256;             // one block per CU, 2 tiles each
constexpr int GRAM_ELEMS = C2 * C2 + C2;   // 16512 (Gram + colsum)
__device__ constexpr double R1d = (double)NEDGE;       // BN1/BN2 row count
__device__ constexpr double R3d = (double)(NB * NPT);  // BN3 row count

using half2_t = _Float16 __attribute__((ext_vector_type(2)));
using half4_t = _Float16 __attribute__((ext_vector_type(4)));
using float4_t = float __attribute__((ext_vector_type(4)));

static __device__ __forceinline__ unsigned long long ullmin2(unsigned long long a, unsigned long long b) {
  return a < b ? a : b;
}

// ---------------- kNN v10 (r20 form, 67us proven) ----------------
__global__ __launch_bounds__(256) void knn_kernel(const float* __restrict__ pos, unsigned short* __restrict__ idxo) {
  __shared__ unsigned long long surv[4][128];   // 4 KiB
  int t = threadIdx.x;
  int lane = t & 63, w = t >> 6;
  int bn = blockIdx.x * 4 + w;            // 8192 blocks x 4 waves = 32768 queries
  int b = bn >> 11, n = bn & (NPT - 1);
  const float* pb = pos + (size_t)b * NPT * 3;
  float xn = pb[n * 3], yn = pb[n * 3 + 1], zn = pb[n * 3 + 2];
  float sqn = xn * xn + yn * yn + zn * zn;

  unsigned long long key[32];
  unsigned dmin = 0xffffffffu;
  #pragma unroll
  for (int i = 0; i < 32; ++i) {
    int m = i * 64 + lane;
    float xm = pb[m * 3], ym = pb[m * 3 + 1], zm = pb[m * 3 + 2];
    float sqm = xm * xm + ym * ym + zm * zm;
    float dt = xn * xm + yn * ym + zn * zm;
    float d = sqn + sqm - 2.0f * dt;
    unsigned ub = __float_as_uint(d);
    ub = (ub & 0x80000000u) ? ~ub : (ub | 0x80000000u);  // order-preserving map
    key[i] = ((unsigned long long)ub << 32) | (unsigned long long)(unsigned)m;
    dmin = dmin < ub ? dmin : ub;
  }

  // bitonic sort of the 64 lane-min dist-bits (u32, ascending by lane)
  unsigned v = dmin;
  #pragma unroll
  for (int k = 2; k <= 64; k <<= 1) {
    #pragma unroll
    for (int j = k >> 1; j > 0; j >>= 1) {
      unsigned o = (unsigned)__shfl_xor((int)v, j, 64);
      bool up = ((lane & k) == 0);
      bool lower = ((lane & j) == 0);
      unsigned mn = v < o ? v : o;
      unsigned mx = v < o ? o : v;
      v = (lower == up) ? mn : mx;
    }
  }
  unsigned d20 = (unsigned)__shfl((int)v, 19, 64);  // 20th smallest lane-min dist-bits

  // compact survivors (distbits <= d20) into LDS
  unsigned long long* sv = surv[w];
  unsigned total = 0;
  #pragma unroll
  for (int i = 0; i < 32; ++i) {
    bool p = (unsigned)(key[i] >> 32) <= d20;
    unsigned long long mask = __ballot(p);
    unsigned pre = __builtin_amdgcn_mbcnt_hi((unsigned)(mask >> 32),
                   __builtin_amdgcn_mbcnt_lo((unsigned)mask, 0));
    unsigned posi = total + pre;
    if (p && posi < 128u) sv[posi] = key[i];
    total += (unsigned)__popcll(mask);
  }

  if (total <= 64u) {
    unsigned long long s = (lane < (int)total) ? sv[lane] : ~0ull;
    #pragma unroll
    for (int k = 2; k <= 64; k <<= 1) {
      #pragma unroll
      for (int j = k >> 1; j > 0; j >>= 1) {
        unsigned long long o = (unsigned long long)__shfl_xor((long long)s, j, 64);
        bool up = ((lane & k) == 0);
        bool lower = ((lane & j) == 0);
        unsigned long long mn = s < o ? s : o;
        unsigned long long mx = s < o ? o : s;
        s = (lower == up) ? mn : mx;
      }
    }
    if (lane < KK) idxo[(size_t)bn * KK + lane] = (unsigned short)(unsigned)(s & 0xffffffffull);
    return;
  }

  unsigned long long T = 0;
  int myidx = 0;
  if (total <= 128u) {
    unsigned long long s0 = (lane < (int)total) ? sv[lane] : ~0ull;
    unsigned long long s1 = (lane + 64 < (int)total) ? sv[lane + 64] : ~0ull;
    for (int r = 0; r < KK; ++r) {
      unsigned long long best = ullmin2(s0 - T, s1 - T);  // consumed (<T) wrap high
      #pragma unroll
      for (int off = 32; off > 0; off >>= 1) {
        unsigned long long o = (unsigned long long)__shfl_xor((long long)best, off, 64);
        best = ullmin2(best, o);
      }
      unsigned long long winner = best + T;
      if (lane == r) myidx = (int)(unsigned)(winner & 0xffffffffull);
      T = winner + 1;
    }
  } else {
    for (int r = 0; r < KK; ++r) {
      unsigned long long u0[16];
      #pragma unroll
      for (int i = 0; i < 16; ++i)
        u0[i] = ullmin2(key[2 * i] - T, key[2 * i + 1] - T);
      #pragma unroll
      for (int s = 8; s > 0; s >>= 1)
        #pragma unroll
        for (int i = 0; i < 8; ++i)
          if (i < s) u0[i] = ullmin2(u0[i], u0[i + s]);
      unsigned long long best = u0[0];
      #pragma unroll
      for (int off = 32; off > 0; off >>= 1) {
        unsigned long long o = (unsigned long long)__shfl_xor((long long)best, off, 64);
        best = ullmin2(best, o);
      }
      unsigned long long winner = best + T;
      if (lane == r) myidx = (int)(unsigned)(winner & 0xffffffffull);
      T = winner + 1;
    }
  }
  if (lane < KK) idxo[(size_t)bn * KK + lane] = (unsigned short)(unsigned)myidx;
}

// ---------------- edge-feature first/second moments (6 + 21 doubles) ----------------
__global__ __launch_bounds__(256) void statse_kernel(const float* __restrict__ pos, const unsigned short* __restrict__ idx,
                                                     double* __restrict__ dstats) {
  float acc[27];
  #pragma unroll
  for (int i = 0; i < 27; ++i) acc[i] = 0.f;
  int t = threadIdx.x;
  for (int e = blockIdx.x * 256 + t; e < NEDGE; e += gridDim.x * 256) {
    int bn = e / KK;
    int b = bn >> 11, n = bn & (NPT - 1);
    int j = idx[e];
    const float* pb = pos + (size_t)b * NPT * 3;
    float f[6];
    f[0] = pb[n * 3]; f[1] = pb[n * 3 + 1]; f[2] = pb[n * 3 + 2];
    f[3] = pb[j * 3] - f[0]; f[4] = pb[j * 3 + 1] - f[1]; f[5] = pb[j * 3 + 2] - f[2];
    int p = 6;
    #pragma unroll
    for (int d = 0; d < 6; ++d) acc[d] += f[d];
    #pragma unroll
    for (int d = 0; d < 6; ++d)
      #pragma unroll
      for (int q = d; q < 6; ++q) { acc[p] += f[d] * f[q]; ++p; }
  }
  __shared__ float sred[4][27];
  int lane = t & 63, w = t >> 6;
  #pragma unroll
  for (int c = 0; c < 27; ++c) {
    float v = acc[c];
    #pragma unroll
    for (int off = 32; off > 0; off >>= 1) v += __shfl_down(v, off);
    if (lane == 0) sred[w][c] = v;
  }
  __syncthreads();
  if (t < 27) {
    double s = (double)sred[0][t] + (double)sred[1][t] + (double)sred[2][t] + (double)sred[3][t];
    atomicAdd(&dstats[t], s);
  }
}

// ---------------- BN1 coeffs from moments ----------------
__global__ void finalize1_kernel(const double* __restrict__ dstats, const float* __restrict__ W1,
                                 const float* __restrict__ b1, const float* __restrict__ g1,
                                 const float* __restrict__ be1, float* __restrict__ scale1,
                                 float* __restrict__ shift1) {
  int c = threadIdx.x;  // 64
  double m1[6], M2[6][6];
  for (int d = 0; d < 6; ++d) m1[d] = dstats[d];
  int p = 6;
  for (int d = 0; d < 6; ++d)
    for (int q = d; q < 6; ++q) { M2[d][q] = dstats[p]; M2[q][d] = dstats[p]; ++p; }
  double w[6];
  for (int d = 0; d < 6; ++d) w[d] = W1[d * C1 + c];
  double wm = 0, quad = 0;
  for (int d = 0; d < 6; ++d) wm += w[d] * m1[d];
  for (int d = 0; d < 6; ++d) {
    double s = 0;
    for (int q = 0; q < 6; ++q) s += M2[d][q] * w[q];
    quad += w[d] * s;
  }
  double bb = b1[c];
  double mean = wm / R1d + bb;
  double E2 = (quad + 2.0 * bb * wm) / R1d + bb * bb;
  double var = E2 - mean * mean;
  double sc = (double)g1[c] / sqrt(var + 1e-5);
  scale1[c] = (float)sc;
  shift1[c] = (float)((double)be1[c] - mean * sc);
}

// ---------------- W3 -> half2 K-paired pack ----------------
__global__ __launch_bounds__(256) void packw3_kernel(const float* __restrict__ W3, half2_t* __restrict__ w3h) {
  int e = blockIdx.x * 256 + threadIdx.x;   // 65536 = 64 kp x 1024 c
  int kp = e >> 10, c = e & 1023;
  float w0 = W3[(size_t)(2 * kp) * EMB + c];
  float w1 = W3[(size_t)(2 * kp + 1) * EMB + c];
  half2_t h; h[0] = (_Float16)w0; h[1] = (_Float16)w1;
  w3h[e] = h;
}

// per-node reduction table
struct NdSel { int rtA, gloA, ghiA, rtB, gloB, ghiB; };
__device__ constexpr NdSel ndtbl[8] = {
  {0, 0, 3, 1, 0, 0}, {1, 1, 3, 2, 0, 1}, {2, 2, 3, 3, 0, 2}, {3, 3, 3, 4, 0, 3},
  {5, 0, 3, 6, 0, 0}, {6, 1, 3, 7, 0, 1}, {7, 2, 3, 8, 0, 2}, {8, 3, 3, 9, 0, 3},
};

// ---------------- fused edge pass v8: BN1-folded weights + bias-in-accumulator ----------------
// Exact transforms vs v6: h = relu(e@(W1*s1) + (b1*s1+sh1)); bias b2 enters as
// MFMA C-init (D = A*B + C) instead of an epilogue add.
__global__ __launch_bounds__(256, 2) void edge2_kernel(const float* __restrict__ pos, const unsigned short* __restrict__ idx,
    const float* __restrict__ W1, const float* __restrict__ b1,
    const float* __restrict__ scale1, const float* __restrict__ shift1,
    const float* __restrict__ W2, const float* __restrict__ b2,
    __half2* __restrict__ am, float* __restrict__ part) {
  constexpr int TROWS = 160;              // 8 nodes x 20 edges
  __shared__ half2_t hp[TROWS * 32];      // 20 KiB  (row, k-pair, swizzled)
  __shared__ float es[TROWS * 8];         // 5 KiB (row stride 8)
  int t = threadIdx.x;
  int lane = t & 63, w = t >> 6;
  int g = lane >> 4, col16 = lane & 15;

  int jp2 = t & 31;
  float s1a = scale1[2 * jp2], sh1a = shift1[2 * jp2];
  float s1b = scale1[2 * jp2 + 1], sh1b = shift1[2 * jp2 + 1];
  float w1a[6], w1b[6];
  #pragma unroll
  for (int d = 0; d < 6; ++d) {
    w1a[d] = W1[d * C1 + 2 * jp2] * s1a;        // BN1 scale folded
    w1b[d] = W1[d * C1 + 2 * jp2 + 1] * s1b;
  }
  float b1a = b1[2 * jp2] * s1a + sh1a;         // BN1 affine folded
  float b1b = b1[2 * jp2 + 1] * s1b + sh1b;

  int wcol[2];
  wcol[0] = (w * 2 + 0) * 16 + col16;
  wcol[1] = (w * 2 + 1) * 16 + col16;
  half4_t bfr[2][4];
  float b2c[2];
  #pragma unroll
  for (int ct = 0; ct < 2; ++ct) {
    b2c[ct] = b2[wcol[ct]];
    #pragma unroll
    for (int s = 0; s < 4; ++s) {
      half4_t bf;
      #pragma unroll
      for (int i = 0; i < 4; ++i)
        bf[i] = (_Float16)W2[(s * 16 + g * 4 + i) * C2 + wcol[ct]];
      bfr[ct][s] = bf;
    }
  }
  float sums[2] = {0.f, 0.f}, sqs[2] = {0.f, 0.f};

  for (int tile = blockIdx.x; tile < NNODE / 8; tile += E2_BLOCKS) {
    if (t < TROWS) {
      int i = t;
      int e = tile * TROWS + i;
      int nd = i / 20;
      int bnode = tile * 8 + nd;
      int b = bnode >> 11, n = bnode & (NPT - 1);
      int j = idx[e];
      const float* pb = pos + (size_t)b * NPT * 3;
      float xi0 = pb[n * 3], xi1 = pb[n * 3 + 1], xi2 = pb[n * 3 + 2];
      float xj0 = pb[j * 3], xj1 = pb[j * 3 + 1], xj2 = pb[j * 3 + 2];
      *(float4*)&es[i * 8] = make_float4(xi0, xi1, xi2, xj0 - xi0);
      *(float2*)&es[i * 8 + 4] = make_float2(xj1 - xi1, xj2 - xi2);
    }
    __syncthreads();
    #pragma unroll
    for (int i = 0; i < 20; ++i) {
      int row = (t >> 5) + 8 * i;
      float4 e0 = *(const float4*)&es[row * 8];
      float2 e1 = *(const float2*)&es[row * 8 + 4];
      float a = b1a + e0.x * w1a[0] + e0.y * w1a[1] + e0.z * w1a[2]
                    + e0.w * w1a[3] + e1.x * w1a[4] + e1.y * w1a[5];
      float bvl = b1b + e0.x * w1b[0] + e0.y * w1b[1] + e0.z * w1b[2]
                      + e0.w * w1b[3] + e1.x * w1b[4] + e1.y * w1b[5];
      a = a > 0.f ? a : 0.f;
      bvl = bvl > 0.f ? bvl : 0.f;
      half2_t hh; hh[0] = (_Float16)a; hh[1] = (_Float16)bvl;
      hp[row * 32 + (jp2 ^ ((row & 7) << 2))] = hh;   // swizzled store
    }
    __syncthreads();
    float4_t acc[2][10];
    #pragma unroll
    for (int ct = 0; ct < 2; ++ct)
      #pragma unroll
      for (int rt = 0; rt < 10; ++rt)
        acc[ct][rt] = (float4_t){b2c[ct], b2c[ct], b2c[ct], b2c[ct]};  // bias as C-init
    #pragma unroll
    for (int rt = 0; rt < 10; ++rt) {
      int arow = rt * 16 + col16;
      int sw = (arow & 7) << 2;
      half4_t afr[4];
      #pragma unroll
      for (int s = 0; s < 4; ++s)
        afr[s] = *(const half4_t*)&hp[arow * 32 + ((s * 8 + g * 2) ^ sw)];  // swizzled load
      #pragma unroll
      for (int s = 0; s < 4; ++s) {
        acc[0][rt] = __builtin_amdgcn_mfma_f32_16x16x16f16(afr[s], bfr[0][s], acc[0][rt], 0, 0, 0);
        acc[1][rt] = __builtin_amdgcn_mfma_f32_16x16x16f16(afr[s], bfr[1][s], acc[1][rt], 0, 0, 0);
      }
    }
    #pragma unroll
    for (int ct = 0; ct < 2; ++ct) {
      float m4[10], n4[10];
      float ssum = 0.f, ssq = 0.f;
      #pragma unroll
      for (int rt = 0; rt < 10; ++rt) {
        float v0 = acc[ct][rt][0];
        float v1 = acc[ct][rt][1];
        float v2 = acc[ct][rt][2];
        float v3 = acc[ct][rt][3];
        m4[rt] = fmaxf(fmaxf(v0, v1), fmaxf(v2, v3));
        n4[rt] = fminf(fminf(v0, v1), fminf(v2, v3));
        ssum += (v0 + v1) + (v2 + v3);
        ssq += v0 * v0 + v1 * v1 + v2 * v2 + v3 * v3;
      }
      sums[ct] += ssum; sqs[ct] += ssq;
      #pragma unroll
      for (int nd = 0; nd < 8; ++nd) {
        NdSel e = ndtbl[nd];
        float mv = (g >= e.gloA && g <= e.ghiA) ? m4[e.rtA] : -FLT_MAX;
        float nv = (g >= e.gloA && g <= e.ghiA) ? n4[e.rtA] : FLT_MAX;
        if (g >= e.gloB && g <= e.ghiB) {
          mv = fmaxf(mv, m4[e.rtB]);
          nv = fminf(nv, n4[e.rtB]);
        }
        #pragma unroll
        for (int off = 16; off <= 32; off <<= 1) {
          mv = fmaxf(mv, __shfl_xor(mv, off, 64));
          nv = fminf(nv, __shfl_xor(nv, off, 64));
        }
        if (g == 0) {
          int node = tile * 8 + nd;
          am[(size_t)node * C2 + wcol[ct]] = __floats2half2_rn(mv, nv);
        }
      }
    }
    __syncthreads();
  }
  #pragma unroll
  for (int ct = 0; ct < 2; ++ct) {
    float s = sums[ct], q = sqs[ct];
    #pragma unroll
    for (int off = 16; off <= 32; off <<= 1) {
      s += __shfl_xor(s, off, 64);
      q += __shfl_xor(q, off, 64);
    }
    if (g == 0) {
      part[(size_t)blockIdx.x * 256 + wcol[ct]] = s;
      part[(size_t)blockIdx.x * 256 + 128 + wcol[ct]] = q;
    }
  }
}

// ---------------- BN2 finalize ----------------
__global__ __launch_bounds__(256) void finalize2_kernel(const float* __restrict__ part,
                                 const float* __restrict__ g2w, const float* __restrict__ be2,
                                 float* __restrict__ scale2, float* __restrict__ shift2) {
  int c = blockIdx.x;   // 128
  int t = threadIdx.x;  // 256
  double s = 0, q = 0;
  for (int i = t; i < N_E2_PART; i += 256) {
    s += (double)part[(size_t)i * 256 + c];
    q += (double)part[(size_t)i * 256 + 128 + c];
  }
  __shared__ double shs[256], shq[256];
  shs[t] = s; shq[t] = q; __syncthreads();
  for (int off = 128; off > 0; off >>= 1) {
    if (t < off) { shs[t] += shs[t + off]; shq[t] += shq[t + off]; }
    __syncthreads();
  }
  if (t == 0) {
    double mean = shs[0] / R1d;
    double var = shq[0] / R1d - mean * mean;
    double sc = (double)g2w[c] / sqrt(var + 1e-5);
    scale2[c] = (float)sc;
    shift2[c] = (float)((double)be2[c] - mean * sc);
  }
}

// node value on the fly: relu(scale * (scale>=0 ? max : min) + shift)
static __device__ __forceinline__ float node_val(__half2 h2, float s, float sh) {
  float A = __low2float(h2), N = __high2float(h2);
  float v = (s >= 0.f ? A : N) * s + sh;
  return v > 0.f ? v : 0.f;
}

// ---------------- Gram partials v2: 1024 threads, 256 blocks ----------------
__global__ __launch_bounds__(1024) void gram_part_kernel(const __half2* __restrict__ am,
                                                         const float* __restrict__ scale2, const float* __restrict__ shift2,
                                                         float* __restrict__ part) {
  __shared__ float tile[64 * C2];  // 32 KiB
  __shared__ float s_s[C2], s_h[C2];
  int t = threadIdx.x;
  if (t < C2) { s_s[t] = scale2[t]; s_h[t] = shift2[t]; }
  __syncthreads();
  int i = t & 127, jh = t >> 7;    // jh in 0..7 (16 cols each)
  float acc[16];
  #pragma unroll
  for (int u = 0; u < 16; ++u) acc[u] = 0.f;
  float csum = 0.f;
  for (int tl = blockIdx.x; tl < NNODE / 64; tl += GRAM_GRID) {
    const __half2* a2 = am + (size_t)tl * 64 * C2;
    #pragma unroll
    for (int q = 0; q < 8; ++q) {
      int e = q * 1024 + t;
      int c = e & 127;
      tile[e] = node_val(a2[e], s_s[c], s_h[c]);
    }
    __syncthreads();
    #pragma unroll 4
    for (int r = 0; r < 64; ++r) {
      float xi = tile[r * C2 + i];
      const float4* row4 = (const float4*)&tile[r * C2 + jh * 16];
      #pragma unroll
      for (int u4 = 0; u4 < 4; ++u4) {
        float4 v = row4[u4];
        acc[u4 * 4 + 0] += xi * v.x;
        acc[u4 * 4 + 1] += xi * v.y;
        acc[u4 * 4 + 2] += xi * v.z;
        acc[u4 * 4 + 3] += xi * v.w;
      }
    }
    if (t < 128) {
      #pragma unroll 8
      for (int r = 0; r < 64; ++r) csum += tile[r * C2 + t];
    }
    __syncthreads();
  }
  float* pb = part + (size_t)blockIdx.x * GRAM_ELEMS;
  float4* pout = (float4*)(pb + (size_t)i * C2 + jh * 16);
  #pragma unroll
  for (int u4 = 0; u4 < 4; ++u4)
    pout[u4] = make_float4(acc[u4 * 4], acc[u4 * 4 + 1], acc[u4 * 4 + 2], acc[u4 * 4 + 3]);
  if (t < 128) pb[C2 * C2 + t] = csum;
}

// ---------------- Gram reduce ----------------
__global__ __launch_bounds__(256) void gram_reduce_kernel(const float* __restrict__ part,
                                                          double* __restrict__ G2, double* __restrict__ nodesum) {
  int e = blockIdx.x * 256 + threadIdx.x;
  if (e >= GRAM_ELEMS) return;
  double s = 0;
  for (int p = 0; p < GRAM_GRID; ++p) s += (double)part[(size_t)p * GRAM_ELEMS + e];
  if (e < C2 * C2) G2[e] = s;
  else nodesum[e - C2 * C2] = s;
}

// ---------------- BN3 coeffs from Gram ----------------
__global__ __launch_bounds__(128) void finalize3_kernel(const double* __restrict__ G2, const double* __restrict__ nodesum,
    const float* __restrict__ W3, const float* __restrict__ b3,
    const float* __restrict__ g3, const float* __restrict__ be3,
    float* __restrict__ scale3, float* __restrict__ shift3) {
  int c = blockIdx.x;   // 1024 channels
  int t = threadIdx.x;  // 128
  __shared__ double wsh[128];
  __shared__ double sh[128];
  double w = W3[(size_t)t * EMB + c];
  wsh[t] = w;
  __syncthreads();
  double rowdot = 0;
  for (int j = 0; j < 128; ++j) rowdot += G2[(size_t)j * C2 + t] * wsh[j];
  sh[t] = w * rowdot;
  __syncthreads();
  for (int off = 64; off > 0; off >>= 1) { if (t < off) sh[t] += sh[t + off]; __syncthreads(); }
  double quad = sh[0];
  __syncthreads();
  sh[t] = w * nodesum[t];
  __syncthreads();
  for (int off = 64; off > 0; off >>= 1) { if (t < off) sh[t] += sh[t + off]; __syncthreads(); }
  if (t == 0) {
    double wm = sh[0];
    double bb = b3[c];
    double mean = wm / R3d + bb;
    double E2 = (quad + 2.0 * bb * wm) / R3d + bb * bb;
    double var = E2 - mean * mean;
    double sc = (double)g3[c] / sqrt(var + 1e-5);
    scale3[c] = (float)sc;
    shift3[c] = (float)((double)be3[c] - mean * sc);
  }
}

// ---------------- linear1 apply v6: single block per row-tile (1024 cols), bias-in-acc ----------------
__global__ __launch_bounds__(256) void apply3pool_kernel(const __half2* __restrict__ am,
    const float* __restrict__ scale2, const float* __restrict__ shift2,
    const half2_t* __restrict__ w3h, const float* __restrict__ b3,
    const float* __restrict__ scale3, const float* __restrict__ shift3,
    float* __restrict__ pp, float* __restrict__ ps) {
  __shared__ half2_t tileh[32 * 64];  // 8 KiB (row, kp, swizzled)
  __shared__ float s_s[C2], s_h[C2];
  int rt = blockIdx.x;  // 1024 row tiles of 32 rows
  int t = threadIdx.x;
  if (t < C2) { s_s[t] = scale2[t]; s_h[t] = shift2[t]; }
  __syncthreads();
  const __half2* a2 = am + (size_t)rt * 32 * C2;
  #pragma unroll
  for (int q = 0; q < 8; ++q) {
    int e = q * 256 + t;
    int row = e >> 6, kp = e & 63;
    __half2 h0 = a2[row * C2 + 2 * kp];
    __half2 h1 = a2[row * C2 + 2 * kp + 1];
    float v0 = node_val(h0, s_s[2 * kp], s_h[2 * kp]);
    float v1 = node_val(h1, s_s[2 * kp + 1], s_h[2 * kp + 1]);
    half2_t hh; hh[0] = (_Float16)v0; hh[1] = (_Float16)v1;
    tileh[row * 64 + (kp ^ ((row & 7) << 2))] = hh;   // swizzled store
  }
  __syncthreads();

  int lane = t & 63, w = t >> 6;
  int rowq = lane >> 4;
  int col16 = lane & 15;
  half4_t afr[2][8];
  #pragma unroll
  for (int rt16 = 0; rt16 < 2; ++rt16) {
    #pragma unroll
    for (int s = 0; s < 8; ++s) {
      int row = rt16 * 16 + col16;
      int jp0 = s * 8 + rowq * 2;
      afr[rt16][s] = *(const half4_t*)&tileh[row * 64 + (jp0 ^ ((row & 7) << 2))];  // swizzled load
    }
  }
  for (int ci = 0; ci < 16; ++ci) {
    int c = (w * 16 + ci) * 16 + col16;   // global channel (block covers all 1024)
    float b3c = b3[c], s3c = scale3[c], sh3c = shift3[c];
    float4_t acc0 = {b3c, b3c, b3c, b3c}, acc1 = {b3c, b3c, b3c, b3c};  // bias as C-init
    #pragma unroll
    for (int s = 0; s < 8; ++s) {
      int jp0 = s * 8 + rowq * 2;
      half2_t b0 = w3h[(size_t)(jp0 + 0) * EMB + c];
      half2_t b1 = w3h[(size_t)(jp0 + 1) * EMB + c];
      half4_t bf; bf[0] = b0[0]; bf[1] = b0[1]; bf[2] = b1[0]; bf[3] = b1[1];
      acc0 = __builtin_amdgcn_mfma_f32_16x16x16f16(afr[0][s], bf, acc0, 0, 0, 0);
      acc1 = __builtin_amdgcn_mfma_f32_16x16x16f16(afr[1][s], bf, acc1, 0, 0, 0);
    }
    float mx = 0.f, sm = 0.f;   // post-ReLU >= 0
    #pragma unroll
    for (int j = 0; j < 4; ++j) {
      float x0 = acc0[j] * s3c + sh3c; x0 = x0 > 0.f ? x0 : 0.f;
      float x1 = acc1[j] * s3c + sh3c; x1 = x1 > 0.f ? x1 : 0.f;
      mx = fmaxf(mx, fmaxf(x0, x1));
      sm += x0 + x1;
    }
    #pragma unroll
    for (int off = 16; off <= 32; off <<= 1) {
      float mo = __shfl_xor(mx, off, 64);
      float so = __shfl_xor(sm, off, 64);
      mx = fmaxf(mx, mo);
      sm += so;
    }
    if (rowq == 0) {
      pp[(size_t)rt * EMB + c] = mx;
      ps[(size_t)rt * EMB + c] = sm;
    }
  }
}

// ---------------- pool reduce ----------------
__global__ __launch_bounds__(256) void poolreduce_kernel(const float* __restrict__ pp, const float* __restrict__ ps,
                                                         float* __restrict__ pmaxo, float* __restrict__ psumo) {
  int e = blockIdx.x * 256 + threadIdx.x;  // e = b*1024 + c, grid 64
  int b = e >> 10, c = e & 1023;
  const float* bp = pp + ((size_t)b * 64) * EMB + c;
  const float* bs = ps + ((size_t)b * 64) * EMB + c;
  float mx = 0.f, sm = 0.f;
  #pragma unroll 8
  for (int tl = 0; tl < 64; ++tl) {
    float v = bp[(size_t)tl * EMB];
    float s = bs[(size_t)tl * EMB];
    mx = mx > v ? mx : v;
    sm += s;
  }
  pmaxo[e] = mx;
  psumo[e] = sm;
}

// ---------------- final linear ----------------
__global__ __launch_bounds__(64) void final_kernel(const float* __restrict__ pmax, const float* __restrict__ psum,
    const float* __restrict__ W4, const float* __restrict__ b4, float* __restrict__ out) {
  int b = blockIdx.x, t = threadIdx.x;
  #pragma unroll
  for (int o = 0; o < OUT; ++o) {
    float acc = 0.f;
    for (int tt = t; tt < 2 * EMB; tt += 64) {
      float p = (tt < EMB) ? pmax[(size_t)b * EMB + tt]
                           : psum[(size_t)b * EMB + tt - EMB] * (1.0f / (float)NPT);
      acc += p * W4[(size_t)tt * OUT + o];
    }
    #pragma unroll
    for (int off = 32; off > 0; off >>= 1) acc += __shfl_down(acc, off);
    if (t == 0) out[b * OUT + o] = acc + b4[o];
  }
}

extern "C" void kernel_launch(void* const* d_in, const int* in_sizes, int n_in,
                              void* d_out, int out_size, void* d_ws, size_t ws_size,
                              hipStream_t stream) {
  const float* pos = (const float*)d_in[0];
  const float* W1 = (const float*)d_in[1];  const float* b1 = (const float*)d_in[2];
  const float* g1 = (const float*)d_in[3];  const float* be1 = (const float*)d_in[4];
  const float* W2 = (const float*)d_in[5];  const float* b2 = (const float*)d_in[6];
  const float* g2 = (const float*)d_in[7];  const float* be2 = (const float*)d_in[8];
  const float* W3 = (const float*)d_in[9];  const float* b3 = (const float*)d_in[10];
  const float* g3 = (const float*)d_in[11]; const float* be3 = (const float*)d_in[12];
  const float* W4 = (const float*)d_in[13]; const float* b4 = (const float*)d_in[14];
  float* out = (float*)d_out;

  // ---- workspace layout, total ~34.7 MiB (35.06 MiB proven safe in round 2) ----
  char* ws = (char*)d_ws;
  unsigned short* idx = (unsigned short*)ws;               // NEDGE u16 = 1.25 MiB
  __half2* am = (__half2*)(ws + (size_t)NEDGE * 2);        // NNODE*C2 half2 = 16 MiB
  char* smallbase = (char*)(am + (size_t)NNODE * C2);

  double* dstats  = (double*)smallbase;           // 32 (27 used)
  double* G2      = dstats + 32;                  // 16384
  double* nodesum = G2 + 16384;                   // 128
  float* scale1 = (float*)(nodesum + 128);
  float* shift1 = scale1 + C1;
  float* scale2 = shift1 + C1;
  float* shift2 = scale2 + C2;
  float* scale3 = shift2 + C2;
  float* shift3 = scale3 + EMB;
  float* pooledmax = shift3 + EMB;                // 16*1024
  float* pooledsum = pooledmax + NB * EMB;        // 16*1024
  half2_t* w3h = (half2_t*)(pooledsum + NB * EMB);// 64*1024 half2 = 256 KiB
  char* scratch = (char*)(w3h + 64 * EMB);
  // lifetime-disjoint overlays on one ~16.9 MiB slab:
  float* eg_part   = (float*)scratch;             // 1024*256*4  = 1.00 MiB (edge2 -> finalize2)
  float* gram_part = (float*)scratch;             // 256*16512*4 = 16.9 MiB (gram_part -> gram_reduce)
  float* pp        = (float*)scratch;             // 1024*1024*4 = 4 MiB    (apply3pool -> poolreduce)
  float* psb       = pp + (size_t)1024 * EMB;     // 4 MiB

  hipMemsetAsync(dstats, 0, 32 * sizeof(double), stream);

  knn_kernel<<<NB * NPT / 4, 256, 0, stream>>>(pos, idx);
  packw3_kernel<<<64 * EMB / 256, 256, 0, stream>>>(W3, w3h);
  statse_kernel<<<512, 256, 0, stream>>>(pos, idx, dstats);
  finalize1_kernel<<<1, 64, 0, stream>>>(dstats, W1, b1, g1, be1, scale1, shift1);
  edge2_kernel<<<E2_BLOCKS, 256, 0, stream>>>(pos, idx, W1, b1, scale1, shift1, W2, b2, am, eg_part);
  finalize2_kernel<<<C2, 256, 0, stream>>>(eg_part, g2, be2, scale2, shift2);
  gram_part_kernel<<<GRAM_GRID, 1024, 0, stream>>>(am, scale2, shift2, gram_part);
  gram_reduce_kernel<<<(GRAM_ELEMS + 255) / 256, 256, 0, stream>>>(gram_part, G2, nodesum);
  finalize3_kernel<<<EMB, 128, 0, stream>>>(G2, nodesum, W3, b3, g3, be3, scale3, shift3);
  apply3pool_kernel<<<1024, 256, 0, stream>>>(am, scale2, shift2, w3h, b3, scale3, shift3, pp, psb);
  poolreduce_kernel<<<NB * EMB / 256, 256, 0, stream>>>(pp, psb, pooledmax, pooledsum);
  final_kernel<<<NB, 64, 0, stream>>>(pooledmax, pooledsum, W4, b4, out);
}